// Round 5
// baseline (167.436 us; speedup 1.0000x reference)
//
#include <hip/hip_runtime.h>
#include <hip/hip_bf16.h>
#include <cstdint>
#include <cstddef>

typedef __attribute__((ext_vector_type(8))) short bf16x8;
typedef __attribute__((ext_vector_type(4))) float f32x4;
typedef unsigned int u32;
typedef unsigned short u16;

__device__ __forceinline__ u16 f2bf(float f) {
  union { float f; u32 u; } v; v.f = f;
  u32 r = v.u + 0x7FFFu + ((v.u >> 16) & 1u);   // round-nearest-even
  return (u16)(r >> 16);
}
__device__ __forceinline__ u32 pk2(float a, float b) {
  return (u32)f2bf(a) | ((u32)f2bf(b) << 16);
}

// ---------------------------------------------------------------------------
// Kernel 1: pe bilinear upsample (half-pixel, clamp) + xp = x + 0.025*pe.
// Writes xp f32 [b][c][n] and xpT bf16 [b][n][c] (LDS transpose).
// ---------------------------------------------------------------------------
__global__ __launch_bounds__(256) void k_prep(const float* __restrict__ x,
                                              const float* __restrict__ pos,
                                              float* __restrict__ xp,
                                              u16* __restrict__ xpT) {
  __shared__ float tile[64][65];
  int t = threadIdx.x;
  int n0 = blockIdx.x * 64;
  int c0 = blockIdx.y * 64;
  int bb = blockIdx.z;
  int h = n0 >> 6;
  float sy = 0.5f * (float)h - 0.25f;
  int y0 = (int)floorf(sy);
  float fy = sy - (float)y0;
  int y0c = y0 < 0 ? 0 : y0;
  int y1c = (y0 + 1 > 31) ? 31 : y0 + 1;

  int cl = t >> 2, nq = t & 3;
  int c = c0 + cl;
  const float* pr0 = pos + (size_t)c * 1024 + y0c * 32;
  const float* pr1 = pos + (size_t)c * 1024 + y1c * 32;
  size_t gbase = ((size_t)(bb * 128 + c)) * 4096 + n0;
#pragma unroll
  for (int u = 0; u < 4; ++u) {
    int nl = nq * 16 + u * 4;
    float4 xv = *(const float4*)(x + gbase + nl);
    float vals[4] = {xv.x, xv.y, xv.z, xv.w};
#pragma unroll
    for (int j = 0; j < 4; ++j) {
      int w = nl + j;                      // w coord (h fixed per block)
      float sx = 0.5f * (float)w - 0.25f;
      int xi = (int)floorf(sx);
      float fx = sx - (float)xi;
      int x0c = xi < 0 ? 0 : xi;
      int x1c = (xi + 1 > 31) ? 31 : xi + 1;
      float top = (1.f - fx) * pr0[x0c] + fx * pr0[x1c];
      float bot = (1.f - fx) * pr1[x0c] + fx * pr1[x1c];
      float pe = (1.f - fy) * top + fy * bot;
      float xe = vals[j] + 0.025f * pe;    // scale_factor(0.25)*0.1
      vals[j] = xe;
      tile[cl][nl + j] = xe;
    }
    float4 st = {vals[0], vals[1], vals[2], vals[3]};
    *(float4*)(xp + gbase + nl) = st;
  }
  __syncthreads();
  // transpose out: thread -> one n row, 16 c values
  int nl = t & 63, qr = t >> 6;
  int n = n0 + nl;
  u32 wbuf[8];
#pragma unroll
  for (int p = 0; p < 8; ++p)
    wbuf[p] = pk2(tile[qr * 16 + 2 * p][nl], tile[qr * 16 + 2 * p + 1][nl]);
  size_t tb = (((size_t)bb * 4096) + n) * 128 + c0 + qr * 16;
  uint4 w0 = {wbuf[0], wbuf[1], wbuf[2], wbuf[3]};
  uint4 w1 = {wbuf[4], wbuf[5], wbuf[6], wbuf[7]};
  *(uint4*)(xpT + tb) = w0;
  *(uint4*)(xpT + tb + 8) = w1;
}

// ---------------------------------------------------------------------------
// Kernel 2: concat weights -> bf16 [192][128], bias -> f32 [192]
// ---------------------------------------------------------------------------
__global__ __launch_bounds__(256) void k_wcat(const float* __restrict__ Wq,
    const float* __restrict__ bq, const float* __restrict__ Wk,
    const float* __restrict__ bk, const float* __restrict__ Wv,
    const float* __restrict__ bv, u16* __restrict__ wc, float* __restrict__ bc) {
  int idx = blockIdx.x * 256 + threadIdx.x;
  if (idx < 24576) {
    int row = idx >> 7, col = idx & 127;
    float v = row < 32 ? Wq[row * 128 + col]
            : row < 64 ? Wk[(row - 32) * 128 + col]
                       : Wv[(row - 64) * 128 + col];
    wc[idx] = f2bf(v);
  }
  if (idx < 192)
    bc[idx] = idx < 32 ? bq[idx] : idx < 64 ? bk[idx - 32] : bv[idx - 64];
}

// ---------------------------------------------------------------------------
// Kernel 3: projection GEMM. q rows are pre-scaled by (1/(sqrt(C)+eps))*log2(e)
// so attention works directly in the exp2 domain.
// ---------------------------------------------------------------------------
__global__ __launch_bounds__(256) void k_proj(const u16* __restrict__ xpT,
    const u16* __restrict__ wc, const float* __restrict__ bc,
    u16* __restrict__ qw, u16* __restrict__ kw, u16* __restrict__ vw) {
  int t = threadIdx.x;
  int wv = t >> 6, lane = t & 63, li = lane & 15, g = lane >> 4;
  int n0 = blockIdx.x * 64;
  int b = blockIdx.y;
  const float qscale = 0.088388347648318447f * 1.4426950408889634f;
  f32x4 acc[3][4];
#pragma unroll
  for (int s = 0; s < 3; ++s)
#pragma unroll
    for (int nt = 0; nt < 4; ++nt) acc[s][nt] = (f32x4){0.f, 0.f, 0.f, 0.f};
#pragma unroll
  for (int kc = 0; kc < 4; ++kc) {
    bf16x8 af[3], bfr[4];
#pragma unroll
    for (int s = 0; s < 3; ++s)
      af[s] = *(const bf16x8*)(wc + ((wv * 3 + s) * 16 + li) * 128 + kc * 32 + g * 8);
#pragma unroll
    for (int nt = 0; nt < 4; ++nt)
      bfr[nt] = *(const bf16x8*)(xpT + (((size_t)b * 4096) + n0 + nt * 16 + li) * 128 + kc * 32 + g * 8);
#pragma unroll
    for (int s = 0; s < 3; ++s)
#pragma unroll
      for (int nt = 0; nt < 4; ++nt)
        acc[s][nt] = __builtin_amdgcn_mfma_f32_16x16x32_bf16(af[s], bfr[nt], acc[s][nt], 0, 0, 0);
  }
#pragma unroll
  for (int s = 0; s < 3; ++s) {
    int mts = wv * 3 + s;
    int ob = mts * 16 + g * 4;
    float bias[4];
#pragma unroll
    for (int r = 0; r < 4; ++r) bias[r] = bc[ob + r];
#pragma unroll
    for (int nt = 0; nt < 4; ++nt) {
      int n = n0 + nt * 16 + li;
      float v0 = acc[s][nt][0] + bias[0];
      float v1 = acc[s][nt][1] + bias[1];
      float v2 = acc[s][nt][2] + bias[2];
      float v3 = acc[s][nt][3] + bias[3];
      if (mts < 2) {
        v0 *= qscale; v1 *= qscale; v2 *= qscale; v3 *= qscale;
        uint2 pk; pk.x = pk2(v0, v1); pk.y = pk2(v2, v3);
        *(uint2*)(qw + (((size_t)b * 4096) + n) * 32 + ob) = pk;
      } else if (mts < 4) {
        uint2 pk; pk.x = pk2(v0, v1); pk.y = pk2(v2, v3);
        *(uint2*)(kw + (((size_t)b * 4096) + n) * 32 + (ob - 32)) = pk;
      } else {
        int cv = ob - 64;
        vw[(((size_t)b * 128) + cv + 0) * 4096 + n] = f2bf(v0);
        vw[(((size_t)b * 128) + cv + 1) * 4096 + n] = f2bf(v1);
        vw[(((size_t)b * 128) + cv + 2) * 4096 + n] = f2bf(v2);
        vw[(((size_t)b * 128) + cv + 3) * 4096 + n] = f2bf(v3);
      }
    }
  }
}

// ---------------------------------------------------------------------------
// Kernel 4: flash attention with intra-block KV-split.
// Block = 4 waves, ALL on the SAME 16 q-rows; wave w handles KV [w*1024,(w+1)*1024).
// Swapped QK^T (exp2 domain, defer-max THR=8), per-wave partial (m,l,O),
// flash-combine via LDS at the end. Grid: 1024 blocks -> 4 waves/SIMD.
// ---------------------------------------------------------------------------
__global__ __launch_bounds__(256) void k_attn(const u16* __restrict__ qw,
    const u16* __restrict__ kw, const u16* __restrict__ vw,
    const float* __restrict__ xp, const float* __restrict__ gamma,
    float* __restrict__ out) {
  __shared__ float buf[4][16][132];   // per-wave scaled O^T partials
  __shared__ float lm[4][16];
  __shared__ float ll[4][16];
  __shared__ float linv[16];
  int t = threadIdx.x;
  int wv = t >> 6, lane = t & 63, li = lane & 15, g = lane >> 4;
  int b = blockIdx.y;
  int q0 = blockIdx.x * 16;
  bf16x8 qf = *(const bf16x8*)(qw + (((size_t)b * 4096) + q0 + li) * 32 + g * 8);
  f32x4 ot[8];
#pragma unroll
  for (int ct = 0; ct < 8; ++ct) ot[ct] = (f32x4){0.f, 0.f, 0.f, 0.f};
  float m_run = -1e30f, l_run = 0.f;
  const f32x4 zz = {0.f, 0.f, 0.f, 0.f};
  const u16* kbb = kw + ((size_t)b * 4096) * 32;
  const u16* vbb = vw + ((size_t)b * 128) * 4096;
  int kv_beg = wv * 1024;

  for (int kv0 = kv_beg; kv0 < kv_beg + 1024; kv0 += 32) {
    bf16x8 kf0 = *(const bf16x8*)(kbb + (size_t)(kv0 + li) * 32 + g * 8);
    bf16x8 kf1 = *(const bf16x8*)(kbb + (size_t)(kv0 + 16 + li) * 32 + g * 8);
    // scores already include 1/sqrt(C) * log2(e) (folded into q)
    f32x4 st0 = __builtin_amdgcn_mfma_f32_16x16x32_bf16(kf0, qf, zz, 0, 0, 0);
    f32x4 st1 = __builtin_amdgcn_mfma_f32_16x16x32_bf16(kf1, qf, zz, 0, 0, 0);
    float mx = fmaxf(fmaxf(fmaxf(st0[0], st0[1]), fmaxf(st0[2], st0[3])),
                     fmaxf(fmaxf(st1[0], st1[1]), fmaxf(st1[2], st1[3])));
    mx = fmaxf(mx, __shfl_xor(mx, 16));
    mx = fmaxf(mx, __shfl_xor(mx, 32));
    // defer-max: skip rescale while tile max stays within 2^8 of running max
    bool nofix = __all(mx <= m_run + 8.f);
    if (!nofix) {
      float mnew = fmaxf(m_run, mx);
      float alpha = exp2f(m_run - mnew);
      l_run *= alpha;
#pragma unroll
      for (int ct = 0; ct < 8; ++ct) {
        ot[ct][0] *= alpha; ot[ct][1] *= alpha;
        ot[ct][2] *= alpha; ot[ct][3] *= alpha;
      }
      m_run = mnew;
    }
    float p0[4], p1[4];
    float sum = 0.f;
#pragma unroll
    for (int r = 0; r < 4; ++r) {
      p0[r] = exp2f(st0[r] - m_run);
      p1[r] = exp2f(st1[r] - m_run);
      sum += p0[r] + p1[r];
    }
    sum += __shfl_xor(sum, 16);
    sum += __shfl_xor(sum, 32);
    l_run += sum;
    // pack P to bf16 and redistribute: dst lane (li,g) needs keys g*8..g*8+7
    u32 P0a = pk2(p0[0], p0[1]), P0b = pk2(p0[2], p0[3]);
    u32 P1a = pk2(p1[0], p1[1]), P1b = pk2(p1[2], p1[3]);
    int s0 = ((2 * g) & 3) * 16 + li;
    int s1 = ((2 * g + 1) & 3) * 16 + li;
    u32 a0 = (u32)__shfl((int)P0a, s0);
    u32 a1 = (u32)__shfl((int)P0b, s0);
    u32 a2 = (u32)__shfl((int)P0a, s1);
    u32 a3 = (u32)__shfl((int)P0b, s1);
    u32 b0 = (u32)__shfl((int)P1a, s0);
    u32 b1 = (u32)__shfl((int)P1b, s0);
    u32 b2 = (u32)__shfl((int)P1a, s1);
    u32 b3 = (u32)__shfl((int)P1b, s1);
    union { uint4 u4; bf16x8 v; } pf;
    bool hi = g >= 2;
    pf.u4.x = hi ? b0 : a0;
    pf.u4.y = hi ? b1 : a1;
    pf.u4.z = hi ? b2 : a2;
    pf.u4.w = hi ? b3 : a3;
#pragma unroll
    for (int ct = 0; ct < 8; ++ct) {
      bf16x8 vf = *(const bf16x8*)(vbb + ((size_t)(ct * 16 + li)) * 4096 + kv0 + g * 8);
      ot[ct] = __builtin_amdgcn_mfma_f32_16x16x32_bf16(vf, pf.v, ot[ct], 0, 0, 0);
    }
  }

  // ---- flash-combine across the 4 waves ----
  if (g == 0) { lm[wv][li] = m_run; ll[wv][li] = l_run; }
  __syncthreads();
  float m0 = lm[0][li], m1 = lm[1][li], m2 = lm[2][li], m3 = lm[3][li];
  float mstar = fmaxf(fmaxf(m0, m1), fmaxf(m2, m3));
  float f0 = exp2f(m0 - mstar), f1 = exp2f(m1 - mstar);
  float f2 = exp2f(m2 - mstar), f3 = exp2f(m3 - mstar);
  float lstar = ll[0][li] * f0 + ll[1][li] * f1 + ll[2][li] * f2 + ll[3][li] * f3;
  float myf = (wv == 0) ? f0 : (wv == 1) ? f1 : (wv == 2) ? f2 : f3;
  if (t < 16) linv[li] = 1.f / lstar;   // wave 0, g==0 lanes
#pragma unroll
  for (int ct = 0; ct < 8; ++ct) {
    f32x4 o = ot[ct];
    o[0] *= myf; o[1] *= myf; o[2] *= myf; o[3] *= myf;
    *(f32x4*)&buf[wv][li][ct * 16 + g * 4] = o;
  }
  __syncthreads();
  // reduction + epilogue: thread t -> q-row i = t&15, cols cb..cb+7
  int i = t & 15, cb = (t >> 4) * 8;
  float inv = linv[i];
  float g0 = gamma[0];
  f32x4 sA = {0.f, 0.f, 0.f, 0.f}, sB = {0.f, 0.f, 0.f, 0.f};
#pragma unroll
  for (int w = 0; w < 4; ++w) {
    f32x4 a = *(const f32x4*)&buf[w][i][cb];
    f32x4 c = *(const f32x4*)&buf[w][i][cb + 4];
    sA[0] += a[0]; sA[1] += a[1]; sA[2] += a[2]; sA[3] += a[3];
    sB[0] += c[0]; sB[1] += c[1]; sB[2] += c[2]; sB[3] += c[3];
  }
#pragma unroll
  for (int j = 0; j < 4; ++j) {
    size_t adrA = (((size_t)b * 128) + cb + j) * 4096 + q0 + i;
    size_t adrB = (((size_t)b * 128) + cb + 4 + j) * 4096 + q0 + i;
    out[adrA] = g0 * sA[j] * inv + xp[adrA];
    out[adrB] = g0 * sB[j] * inv + xp[adrB];
  }
}

// ---------------------------------------------------------------------------
extern "C" void kernel_launch(void* const* d_in, const int* in_sizes, int n_in,
                              void* d_out, int out_size, void* d_ws, size_t ws_size,
                              hipStream_t stream) {
  const float* x     = (const float*)d_in[0];
  const float* Wq    = (const float*)d_in[1];
  const float* bq    = (const float*)d_in[2];
  const float* Wk    = (const float*)d_in[3];
  const float* bk    = (const float*)d_in[4];
  const float* Wv    = (const float*)d_in[5];
  const float* bv    = (const float*)d_in[6];
  const float* gamma = (const float*)d_in[7];
  const float* pos   = (const float*)d_in[8];
  float* out = (float*)d_out;

  char* ws = (char*)d_ws;
  float* xp  = (float*)ws;                          //  8,388,608 B  f32 [4][128][4096]
  u16* xpT   = (u16*)(ws + 8388608);                //  4,194,304 B  bf16 [4][4096][128]
  u16* qw    = (u16*)(ws + 12582912);               //  1,048,576 B  bf16 [4][4096][32]
  u16* kw    = (u16*)(ws + 13631488);               //  1,048,576 B  bf16 [4][4096][32]
  u16* vw    = (u16*)(ws + 14680064);               //  4,194,304 B  bf16 [4][128][4096]
  u16* wc    = (u16*)(ws + 18874368);               //     49,152 B  bf16 [192][128]
  float* bc  = (float*)(ws + 18923520);             //        768 B  f32 [192]

  k_prep<<<dim3(64, 2, 4), 256, 0, stream>>>(x, pos, xp, xpT);
  k_wcat<<<96, 256, 0, stream>>>(Wq, bq, Wk, bk, Wv, bv, wc, bc);
  k_proj<<<dim3(64, 4), 256, 0, stream>>>(xpT, wc, bc, qw, kw, vw);
  k_attn<<<dim3(256, 4), 256, 0, stream>>>(qw, kw, vw, xp, gamma, out);
}

// Round 6
// 89.950 us; speedup vs baseline: 1.8614x; 1.8614x over previous
//
#include <hip/hip_runtime.h>
#include <hip/hip_bf16.h>
#include <cstdint>
#include <cstddef>

typedef __attribute__((ext_vector_type(8))) short bf16x8;
typedef __attribute__((ext_vector_type(4))) float f32x4;
typedef unsigned int u32;
typedef unsigned short u16;
typedef unsigned char u8;

__device__ __forceinline__ u16 f2bf(float f) {
  union { float f; u32 u; } v; v.f = f;
  u32 r = v.u + 0x7FFFu + ((v.u >> 16) & 1u);   // round-nearest-even
  return (u16)(r >> 16);
}
__device__ __forceinline__ u32 pk2(float a, float b) {
  return (u32)f2bf(a) | ((u32)f2bf(b) << 16);
}
__device__ __forceinline__ float bfhi(u32 u) {          // high short as f32
  union { u32 u; float f; } v; v.u = u & 0xFFFF0000u; return v.f;
}
__device__ __forceinline__ float bflo(u32 u) {          // low short as f32
  union { u32 u; float f; } v; v.u = u << 16; return v.f;
}

// ---------------------------------------------------------------------------
// Kernel 1: pe bilinear upsample (half-pixel, clamp) + xp = x + 0.025*pe.
// Writes xp f32 [b][c][n] and xpT bf16 [b][n][c] (LDS transpose).
// ---------------------------------------------------------------------------
__global__ __launch_bounds__(256) void k_prep(const float* __restrict__ x,
                                              const float* __restrict__ pos,
                                              float* __restrict__ xp,
                                              u16* __restrict__ xpT) {
  __shared__ float tile[64][65];
  int t = threadIdx.x;
  int n0 = blockIdx.x * 64;
  int c0 = blockIdx.y * 64;
  int bb = blockIdx.z;
  int h = n0 >> 6;
  float sy = 0.5f * (float)h - 0.25f;
  int y0 = (int)floorf(sy);
  float fy = sy - (float)y0;
  int y0c = y0 < 0 ? 0 : y0;
  int y1c = (y0 + 1 > 31) ? 31 : y0 + 1;

  int cl = t >> 2, nq = t & 3;
  int c = c0 + cl;
  const float* pr0 = pos + (size_t)c * 1024 + y0c * 32;
  const float* pr1 = pos + (size_t)c * 1024 + y1c * 32;
  size_t gbase = ((size_t)(bb * 128 + c)) * 4096 + n0;
#pragma unroll
  for (int u = 0; u < 4; ++u) {
    int nl = nq * 16 + u * 4;
    float4 xv = *(const float4*)(x + gbase + nl);
    float vals[4] = {xv.x, xv.y, xv.z, xv.w};
#pragma unroll
    for (int j = 0; j < 4; ++j) {
      int w = nl + j;                      // w coord (h fixed per block)
      float sx = 0.5f * (float)w - 0.25f;
      int xi = (int)floorf(sx);
      float fx = sx - (float)xi;
      int x0c = xi < 0 ? 0 : xi;
      int x1c = (xi + 1 > 31) ? 31 : xi + 1;
      float top = (1.f - fx) * pr0[x0c] + fx * pr0[x1c];
      float bot = (1.f - fx) * pr1[x0c] + fx * pr1[x1c];
      float pe = (1.f - fy) * top + fy * bot;
      float xe = vals[j] + 0.025f * pe;    // scale_factor(0.25)*0.1
      vals[j] = xe;
      tile[cl][nl + j] = xe;
    }
    float4 st = {vals[0], vals[1], vals[2], vals[3]};
    *(float4*)(xp + gbase + nl) = st;
  }
  __syncthreads();
  // transpose out: thread -> one n row, 16 c values
  int nl = t & 63, qr = t >> 6;
  int n = n0 + nl;
  u32 wbuf[8];
#pragma unroll
  for (int p = 0; p < 8; ++p)
    wbuf[p] = pk2(tile[qr * 16 + 2 * p][nl], tile[qr * 16 + 2 * p + 1][nl]);
  size_t tb = (((size_t)bb * 4096) + n) * 128 + c0 + qr * 16;
  uint4 w0 = {wbuf[0], wbuf[1], wbuf[2], wbuf[3]};
  uint4 w1 = {wbuf[4], wbuf[5], wbuf[6], wbuf[7]};
  *(uint4*)(xpT + tb) = w0;
  *(uint4*)(xpT + tb + 8) = w1;
}

// ---------------------------------------------------------------------------
// Kernel 2: concat weights -> bf16 [192][128], bias -> f32 [192]
// ---------------------------------------------------------------------------
__global__ __launch_bounds__(256) void k_wcat(const float* __restrict__ Wq,
    const float* __restrict__ bq, const float* __restrict__ Wk,
    const float* __restrict__ bk, const float* __restrict__ Wv,
    const float* __restrict__ bv, u16* __restrict__ wc, float* __restrict__ bc) {
  int idx = blockIdx.x * 256 + threadIdx.x;
  if (idx < 24576) {
    int row = idx >> 7, col = idx & 127;
    float v = row < 32 ? Wq[row * 128 + col]
            : row < 64 ? Wk[(row - 32) * 128 + col]
                       : Wv[(row - 64) * 128 + col];
    wc[idx] = f2bf(v);
  }
  if (idx < 192)
    bc[idx] = idx < 32 ? bq[idx] : idx < 64 ? bk[idx - 32] : bv[idx - 64];
}

// ---------------------------------------------------------------------------
// Kernel 3: projection GEMM. q rows pre-scaled by (1/(sqrt(C)+eps))*log2(e).
// q,k -> [b][n][32] bf16; v -> fp8 e4m3, K-major tiles [b][n/32][c=128][32].
// ---------------------------------------------------------------------------
__global__ __launch_bounds__(256) void k_proj(const u16* __restrict__ xpT,
    const u16* __restrict__ wc, const float* __restrict__ bc,
    u16* __restrict__ qw, u16* __restrict__ kw, u8* __restrict__ v2) {
  int t = threadIdx.x;
  int wv = t >> 6, lane = t & 63, li = lane & 15, g = lane >> 4;
  int n0 = blockIdx.x * 64;
  int b = blockIdx.y;
  const float qscale = 0.088388347648318447f * 1.4426950408889634f;
  f32x4 acc[3][4];
#pragma unroll
  for (int s = 0; s < 3; ++s)
#pragma unroll
    for (int nt = 0; nt < 4; ++nt) acc[s][nt] = (f32x4){0.f, 0.f, 0.f, 0.f};
#pragma unroll
  for (int kc = 0; kc < 4; ++kc) {
    bf16x8 af[3], bfr[4];
#pragma unroll
    for (int s = 0; s < 3; ++s)
      af[s] = *(const bf16x8*)(wc + ((wv * 3 + s) * 16 + li) * 128 + kc * 32 + g * 8);
#pragma unroll
    for (int nt = 0; nt < 4; ++nt)
      bfr[nt] = *(const bf16x8*)(xpT + (((size_t)b * 4096) + n0 + nt * 16 + li) * 128 + kc * 32 + g * 8);
#pragma unroll
    for (int s = 0; s < 3; ++s)
#pragma unroll
      for (int nt = 0; nt < 4; ++nt)
        acc[s][nt] = __builtin_amdgcn_mfma_f32_16x16x32_bf16(af[s], bfr[nt], acc[s][nt], 0, 0, 0);
  }
#pragma unroll
  for (int s = 0; s < 3; ++s) {
    int mts = wv * 3 + s;
    int ob = mts * 16 + g * 4;
    float bias[4];
#pragma unroll
    for (int r = 0; r < 4; ++r) bias[r] = bc[ob + r];
#pragma unroll
    for (int nt = 0; nt < 4; ++nt) {
      int n = n0 + nt * 16 + li;
      float v0 = acc[s][nt][0] + bias[0];
      float v1 = acc[s][nt][1] + bias[1];
      float v2v = acc[s][nt][2] + bias[2];
      float v3 = acc[s][nt][3] + bias[3];
      if (mts < 2) {
        v0 *= qscale; v1 *= qscale; v2v *= qscale; v3 *= qscale;
        uint2 pk; pk.x = pk2(v0, v1); pk.y = pk2(v2v, v3);
        *(uint2*)(qw + (((size_t)b * 4096) + n) * 32 + ob) = pk;
      } else if (mts < 4) {
        uint2 pk; pk.x = pk2(v0, v1); pk.y = pk2(v2v, v3);
        *(uint2*)(kw + (((size_t)b * 4096) + n) * 32 + (ob - 32)) = pk;
      } else {
        int cv = ob - 64;
        u32 w01 = (u32)__builtin_amdgcn_cvt_pk_fp8_f32(v0, v1, 0, false);
        u32 w23 = (u32)__builtin_amdgcn_cvt_pk_fp8_f32(v2v, v3, 0, false);
        size_t vb = (((size_t)b * 128 + (n >> 5)) * 128 + cv) * 32 + (n & 31);
        v2[vb]      = (u8)(w01 & 0xFF);
        v2[vb + 32] = (u8)((w01 >> 8) & 0xFF);
        v2[vb + 64] = (u8)(w23 & 0xFF);
        v2[vb + 96] = (u8)((w23 >> 8) & 0xFF);
      }
    }
  }
}

// ---------------------------------------------------------------------------
// Kernel 4: flash attention. Block = 4 waves on the SAME 32 q-rows (2 halves
// of 16); wave w handles KV [w*1024,(w+1)*1024) (KV-split x4). Swapped QK^T
// bf16, exp2 domain, defer-max THR=8; P and V in fp8 e4m3 (PV mfma fp8_fp8);
// V is K-major tiled so each iteration's 8 V-loads are one contiguous 4KB.
// Flash-combine via bf16 partials in LDS. Grid: 512 blocks.
// ---------------------------------------------------------------------------
__global__ __launch_bounds__(256) void k_attn(const u16* __restrict__ qw,
    const u16* __restrict__ kw, const u8* __restrict__ v2,
    const float* __restrict__ xp, const float* __restrict__ gamma,
    float* __restrict__ out) {
  __shared__ u32 buf[4][32][66];      // bf16-pair partial O^T per wave
  __shared__ float lm[4][32];
  __shared__ float ll[4][32];
  int t = threadIdx.x;
  int wv = t >> 6, lane = t & 63, li = lane & 15, g = lane >> 4;
  int b = blockIdx.y;
  int q0 = blockIdx.x * 32;
  bf16x8 qfA = *(const bf16x8*)(qw + (((size_t)b * 4096) + q0 + li) * 32 + g * 8);
  bf16x8 qfB = *(const bf16x8*)(qw + (((size_t)b * 4096) + q0 + 16 + li) * 32 + g * 8);
  f32x4 otA[8], otB[8];
#pragma unroll
  for (int ct = 0; ct < 8; ++ct) {
    otA[ct] = (f32x4){0.f, 0.f, 0.f, 0.f};
    otB[ct] = (f32x4){0.f, 0.f, 0.f, 0.f};
  }
  float mA = -1e30f, mB = -1e30f, lA = 0.f, lB = 0.f;
  const f32x4 zz = {0.f, 0.f, 0.f, 0.f};
  const u16* kbb = kw + ((size_t)b * 4096) * 32;
  const u8* vbb = v2 + ((size_t)b * 128) * 4096;   // [128 chunks][128 c][32 k]
  int s0 = ((2 * g) & 3) * 16 + li;
  int s1 = ((2 * g + 1) & 3) * 16 + li;
  bool hi = g >= 2;
  int kv_beg = wv * 1024;

  for (int kv0 = kv_beg; kv0 < kv_beg + 1024; kv0 += 32) {
    bf16x8 kf0 = *(const bf16x8*)(kbb + (size_t)(kv0 + li) * 32 + g * 8);
    bf16x8 kf1 = *(const bf16x8*)(kbb + (size_t)(kv0 + 16 + li) * 32 + g * 8);
    f32x4 sA0 = __builtin_amdgcn_mfma_f32_16x16x32_bf16(kf0, qfA, zz, 0, 0, 0);
    f32x4 sA1 = __builtin_amdgcn_mfma_f32_16x16x32_bf16(kf1, qfA, zz, 0, 0, 0);
    f32x4 sB0 = __builtin_amdgcn_mfma_f32_16x16x32_bf16(kf0, qfB, zz, 0, 0, 0);
    f32x4 sB1 = __builtin_amdgcn_mfma_f32_16x16x32_bf16(kf1, qfB, zz, 0, 0, 0);
    float mxA = fmaxf(fmaxf(fmaxf(sA0[0], sA0[1]), fmaxf(sA0[2], sA0[3])),
                      fmaxf(fmaxf(sA1[0], sA1[1]), fmaxf(sA1[2], sA1[3])));
    float mxB = fmaxf(fmaxf(fmaxf(sB0[0], sB0[1]), fmaxf(sB0[2], sB0[3])),
                      fmaxf(fmaxf(sB1[0], sB1[1]), fmaxf(sB1[2], sB1[3])));
    mxA = fmaxf(mxA, __shfl_xor(mxA, 16));
    mxA = fmaxf(mxA, __shfl_xor(mxA, 32));
    mxB = fmaxf(mxB, __shfl_xor(mxB, 16));
    mxB = fmaxf(mxB, __shfl_xor(mxB, 32));
    bool ok = (mxA <= mA + 8.f) && (mxB <= mB + 8.f);
    if (!__all(ok)) {
      float mnA = fmaxf(mA, mxA), mnB = fmaxf(mB, mxB);
      float aA = exp2f(mA - mnA), aB = exp2f(mB - mnB);
      lA *= aA; lB *= aB;
#pragma unroll
      for (int ct = 0; ct < 8; ++ct) {
        otA[ct][0] *= aA; otA[ct][1] *= aA; otA[ct][2] *= aA; otA[ct][3] *= aA;
        otB[ct][0] *= aB; otB[ct][1] *= aB; otB[ct][2] *= aB; otB[ct][3] *= aB;
      }
      mA = mnA; mB = mnB;
    }
    float pA0[4], pA1[4], pB0[4], pB1[4];
    float sumA = 0.f, sumB = 0.f;
#pragma unroll
    for (int r = 0; r < 4; ++r) {
      pA0[r] = exp2f(sA0[r] - mA);
      pA1[r] = exp2f(sA1[r] - mA);
      pB0[r] = exp2f(sB0[r] - mB);
      pB1[r] = exp2f(sB1[r] - mB);
      sumA += pA0[r] + pA1[r];
      sumB += pB0[r] + pB1[r];
    }
    sumA += __shfl_xor(sumA, 16);
    sumA += __shfl_xor(sumA, 32);
    sumB += __shfl_xor(sumB, 16);
    sumB += __shfl_xor(sumB, 32);
    lA += sumA; lB += sumB;
    // pack P to fp8 (one dword = 4 keys) and redistribute across lane groups
    u32 PA0 = (u32)__builtin_amdgcn_cvt_pk_fp8_f32(pA0[0], pA0[1], 0, false);
    PA0 = (u32)__builtin_amdgcn_cvt_pk_fp8_f32(pA0[2], pA0[3], (int)PA0, true);
    u32 PA1 = (u32)__builtin_amdgcn_cvt_pk_fp8_f32(pA1[0], pA1[1], 0, false);
    PA1 = (u32)__builtin_amdgcn_cvt_pk_fp8_f32(pA1[2], pA1[3], (int)PA1, true);
    u32 PB0 = (u32)__builtin_amdgcn_cvt_pk_fp8_f32(pB0[0], pB0[1], 0, false);
    PB0 = (u32)__builtin_amdgcn_cvt_pk_fp8_f32(pB0[2], pB0[3], (int)PB0, true);
    u32 PB1 = (u32)__builtin_amdgcn_cvt_pk_fp8_f32(pB1[0], pB1[1], 0, false);
    PB1 = (u32)__builtin_amdgcn_cvt_pk_fp8_f32(pB1[2], pB1[3], (int)PB1, true);
    u32 aA0 = (u32)__shfl((int)PA0, s0);
    u32 aA1 = (u32)__shfl((int)PA0, s1);
    u32 bA0 = (u32)__shfl((int)PA1, s0);
    u32 bA1 = (u32)__shfl((int)PA1, s1);
    u32 aB0 = (u32)__shfl((int)PB0, s0);
    u32 aB1 = (u32)__shfl((int)PB0, s1);
    u32 bB0 = (u32)__shfl((int)PB1, s0);
    u32 bB1 = (u32)__shfl((int)PB1, s1);
    union { uint2 u2; long long l; } pfA, pfB;
    pfA.u2.x = hi ? bA0 : aA0;
    pfA.u2.y = hi ? bA1 : aA1;
    pfB.u2.x = hi ? bB0 : aB0;
    pfB.u2.y = hi ? bB1 : aB1;
    const u8* vchunk = vbb + (size_t)(kv0 >> 5) * 4096;
#pragma unroll
    for (int ct = 0; ct < 8; ++ct) {
      union { uint2 u2; long long l; } vf;
      vf.u2 = *(const uint2*)(vchunk + (ct * 16 + li) * 32 + g * 8);
      otA[ct] = __builtin_amdgcn_mfma_f32_16x16x32_fp8_fp8(vf.l, pfA.l, otA[ct], 0, 0, 0);
      otB[ct] = __builtin_amdgcn_mfma_f32_16x16x32_fp8_fp8(vf.l, pfB.l, otB[ct], 0, 0, 0);
    }
  }

  // ---- flash-combine across the 4 waves ----
  if (g == 0) {
    lm[wv][li] = mA; ll[wv][li] = lA;
    lm[wv][16 + li] = mB; ll[wv][16 + li] = lB;
  }
  __syncthreads();
  float msA = fmaxf(fmaxf(lm[0][li], lm[1][li]), fmaxf(lm[2][li], lm[3][li]));
  float msB = fmaxf(fmaxf(lm[0][16 + li], lm[1][16 + li]),
                    fmaxf(lm[2][16 + li], lm[3][16 + li]));
  float myfA = exp2f(mA - msA);
  float myfB = exp2f(mB - msB);
#pragma unroll
  for (int ct = 0; ct < 8; ++ct) {
    uint2 wA, wB;
    wA.x = pk2(otA[ct][0] * myfA, otA[ct][1] * myfA);
    wA.y = pk2(otA[ct][2] * myfA, otA[ct][3] * myfA);
    wB.x = pk2(otB[ct][0] * myfB, otB[ct][1] * myfB);
    wB.y = pk2(otB[ct][2] * myfB, otB[ct][3] * myfB);
    *(uint2*)&buf[wv][li][ct * 8 + g * 2] = wA;
    *(uint2*)&buf[wv][16 + li][ct * 8 + g * 2] = wB;
  }
  __syncthreads();
  // reduction + epilogue: thread t -> q-row i = t&31, cols cb..cb+15
  int i = t & 31, cb = (t >> 5) * 16;
  float m0 = lm[0][i], m1 = lm[1][i], m2 = lm[2][i], m3 = lm[3][i];
  float ms = fmaxf(fmaxf(m0, m1), fmaxf(m2, m3));
  float lstar = ll[0][i] * exp2f(m0 - ms) + ll[1][i] * exp2f(m1 - ms)
              + ll[2][i] * exp2f(m2 - ms) + ll[3][i] * exp2f(m3 - ms);
  float inv = 1.f / lstar;
  float g0 = gamma[0];
  float s[16];
#pragma unroll
  for (int j = 0; j < 16; ++j) s[j] = 0.f;
#pragma unroll
  for (int w = 0; w < 4; ++w) {
    uint4 r0 = *(const uint4*)&buf[w][i][cb / 2];
    uint4 r1 = *(const uint4*)&buf[w][i][cb / 2 + 4];
    s[0] += bflo(r0.x);  s[1] += bfhi(r0.x);
    s[2] += bflo(r0.y);  s[3] += bfhi(r0.y);
    s[4] += bflo(r0.z);  s[5] += bfhi(r0.z);
    s[6] += bflo(r0.w);  s[7] += bfhi(r0.w);
    s[8] += bflo(r1.x);  s[9] += bfhi(r1.x);
    s[10] += bflo(r1.y); s[11] += bfhi(r1.y);
    s[12] += bflo(r1.z); s[13] += bfhi(r1.z);
    s[14] += bflo(r1.w); s[15] += bfhi(r1.w);
  }
#pragma unroll
  for (int j = 0; j < 16; ++j) {
    size_t adr = (((size_t)b * 128) + cb + j) * 4096 + q0 + i;
    out[adr] = g0 * s[j] * inv + xp[adr];
  }
}

// ---------------------------------------------------------------------------
extern "C" void kernel_launch(void* const* d_in, const int* in_sizes, int n_in,
                              void* d_out, int out_size, void* d_ws, size_t ws_size,
                              hipStream_t stream) {
  const float* x     = (const float*)d_in[0];
  const float* Wq    = (const float*)d_in[1];
  const float* bq    = (const float*)d_in[2];
  const float* Wk    = (const float*)d_in[3];
  const float* bk    = (const float*)d_in[4];
  const float* Wv    = (const float*)d_in[5];
  const float* bv    = (const float*)d_in[6];
  const float* gamma = (const float*)d_in[7];
  const float* pos   = (const float*)d_in[8];
  float* out = (float*)d_out;

  char* ws = (char*)d_ws;
  float* xp  = (float*)ws;                          //  8,388,608 B  f32 [4][128][4096]
  u16* xpT   = (u16*)(ws + 8388608);                //  4,194,304 B  bf16 [4][4096][128]
  u16* qw    = (u16*)(ws + 12582912);               //  1,048,576 B  bf16 [4][4096][32]
  u16* kw    = (u16*)(ws + 13631488);               //  1,048,576 B  bf16 [4][4096][32]
  u8*  v2    = (u8*)(ws + 14680064);                //  2,097,152 B  fp8 [4][128][128][32]
  u16* wc    = (u16*)(ws + 16777216);               //     49,152 B  bf16 [192][128]
  float* bc  = (float*)(ws + 16826368);             //        768 B  f32 [192]

  k_prep<<<dim3(64, 2, 4), 256, 0, stream>>>(x, pos, xp, xpT);
  k_wcat<<<96, 256, 0, stream>>>(Wq, bq, Wk, bk, Wv, bv, wc, bc);
  k_proj<<<dim3(64, 4), 256, 0, stream>>>(xpT, wc, bc, qw, kw, v2);
  k_attn<<<dim3(128, 4), 256, 0, stream>>>(qw, kw, v2, xp, gamma, out);
}

// Round 8
// 66.412 us; speedup vs baseline: 2.5212x; 1.3544x over previous
//
#include <hip/hip_runtime.h>
#include <hip/hip_bf16.h>
#include <cstdint>
#include <cstddef>

typedef __attribute__((ext_vector_type(8))) short bf16x8;
typedef __attribute__((ext_vector_type(4))) float f32x4;
typedef __attribute__((ext_vector_type(16))) float f32x16;
typedef __attribute__((ext_vector_type(2))) unsigned int u32x2;
typedef unsigned int u32;
typedef unsigned short u16;
typedef unsigned char u8;

__device__ __forceinline__ u16 f2bf(float f) {
  union { float f; u32 u; } v; v.f = f;
  u32 r = v.u + 0x7FFFu + ((v.u >> 16) & 1u);   // round-nearest-even
  return (u16)(r >> 16);
}
__device__ __forceinline__ u32 pk2(float a, float b) {
  return (u32)f2bf(a) | ((u32)f2bf(b) << 16);
}
__device__ __forceinline__ float bfhi(u32 u) {
  union { u32 u; float f; } v; v.u = u & 0xFFFF0000u; return v.f;
}
__device__ __forceinline__ float bflo(u32 u) {
  union { u32 u; float f; } v; v.u = u << 16; return v.f;
}
__device__ __forceinline__ float fexp2(float x) {
  return __builtin_amdgcn_exp2f(x);
}

// ---------------------------------------------------------------------------
// Kernel 1: concat weights -> bf16 [192][128], bias -> f32 [192]
// ---------------------------------------------------------------------------
__global__ __launch_bounds__(256) void k_wcat(const float* __restrict__ Wq,
    const float* __restrict__ bq, const float* __restrict__ Wk,
    const float* __restrict__ bk, const float* __restrict__ Wv,
    const float* __restrict__ bv, u16* __restrict__ wc, float* __restrict__ bc) {
  int idx = blockIdx.x * 256 + threadIdx.x;
  if (idx < 24576) {
    int row = idx >> 7, col = idx & 127;
    float v = row < 32 ? Wq[row * 128 + col]
            : row < 64 ? Wk[(row - 32) * 128 + col]
                       : Wv[(row - 64) * 128 + col];
    wc[idx] = f2bf(v);
  }
  if (idx < 192)
    bc[idx] = idx < 32 ? bq[idx] : idx < 64 ? bk[idx - 32] : bv[idx - 64];
}

// ---------------------------------------------------------------------------
// Kernel 2 (fused prep+proj): bilinear PE + xp, tile kept in LDS, projection
// GEMM straight from LDS. q pre-scaled by (1/(sqrt(C)+eps))*log2(e).
// q,k -> [b][n][32] bf16; v -> fp8 e4m3 K-major [b][n/32][128][32].
// ---------------------------------------------------------------------------
__global__ __launch_bounds__(256) void k_pp(const float* __restrict__ x,
    const float* __restrict__ pos, const u16* __restrict__ wc,
    const float* __restrict__ bc, float* __restrict__ xp,
    u16* __restrict__ qw, u16* __restrict__ kw, u8* __restrict__ v2) {
  __shared__ float tf[128][66];     // xp tile [c][n]
  __shared__ u16 tb[64][136];       // bf16 [n][c] (pad to 136 for b128 align)
  int t = threadIdx.x;
  int n0 = blockIdx.x * 64;
  int b = blockIdx.y;
  int h = blockIdx.x;               // one image row per tile (W=64)
  float sy = 0.5f * (float)h - 0.25f;
  int y0 = (int)floorf(sy);
  float fy = sy - (float)y0;
  int y0c = y0 < 0 ? 0 : y0;
  int y1c = (y0 + 1 > 31) ? 31 : y0 + 1;
  {
    int cl = t >> 1, half = t & 1;
    const float* pr0 = pos + (size_t)cl * 1024 + y0c * 32;
    const float* pr1 = pos + (size_t)cl * 1024 + y1c * 32;
    size_t gbase = ((size_t)(b * 128 + cl)) * 4096 + n0;
#pragma unroll
    for (int u = 0; u < 8; ++u) {
      int nl = half * 32 + u * 4;
      float4 xv = *(const float4*)(x + gbase + nl);
      float vals[4] = {xv.x, xv.y, xv.z, xv.w};
#pragma unroll
      for (int j = 0; j < 4; ++j) {
        int w = nl + j;
        float sx = 0.5f * (float)w - 0.25f;
        int xi = (int)floorf(sx);
        float fx = sx - (float)xi;
        int x0c = xi < 0 ? 0 : xi;
        int x1c = (xi + 1 > 31) ? 31 : xi + 1;
        float top = (1.f - fx) * pr0[x0c] + fx * pr0[x1c];
        float bot = (1.f - fx) * pr1[x0c] + fx * pr1[x1c];
        float pe = (1.f - fy) * top + fy * bot;
        float xe = vals[j] + 0.025f * pe;   // 0.25 * 0.1
        vals[j] = xe;
        tf[cl][nl + j] = xe;
      }
      float4 st = {vals[0], vals[1], vals[2], vals[3]};
      *(float4*)(xp + gbase + nl) = st;
    }
  }
  __syncthreads();
  {  // transpose-pack f32 [c][n] -> bf16 [n][c]
    int nl = t & 63, qr = t >> 6;
    u32* tbw = (u32*)&tb[0][0];
#pragma unroll
    for (int hc = 0; hc < 2; ++hc) {
      int cbase = qr * 16 + hc * 64;
#pragma unroll
      for (int p = 0; p < 8; ++p)
        tbw[nl * 68 + cbase / 2 + p] =
            pk2(tf[cbase + 2 * p][nl], tf[cbase + 2 * p + 1][nl]);
    }
  }
  __syncthreads();
  // projection: wave wv -> m-tiles wv*3..wv*3+2 of Wcat(192x128)
  int wv = t >> 6, lane = t & 63, li = lane & 15, g = lane >> 4;
  const float qscale = 0.088388347648318447f * 1.4426950408889634f;
  f32x4 acc[3][4];
#pragma unroll
  for (int s = 0; s < 3; ++s)
#pragma unroll
    for (int nt = 0; nt < 4; ++nt) acc[s][nt] = (f32x4){0.f, 0.f, 0.f, 0.f};
#pragma unroll
  for (int kc = 0; kc < 4; ++kc) {
    bf16x8 af[3], bfr[4];
#pragma unroll
    for (int s = 0; s < 3; ++s)
      af[s] = *(const bf16x8*)(wc + ((wv * 3 + s) * 16 + li) * 128 + kc * 32 + g * 8);
#pragma unroll
    for (int nt = 0; nt < 4; ++nt)
      bfr[nt] = *(const bf16x8*)&tb[nt * 16 + li][kc * 32 + g * 8];
#pragma unroll
    for (int s = 0; s < 3; ++s)
#pragma unroll
      for (int nt = 0; nt < 4; ++nt)
        acc[s][nt] = __builtin_amdgcn_mfma_f32_16x16x32_bf16(af[s], bfr[nt], acc[s][nt], 0, 0, 0);
  }
#pragma unroll
  for (int s = 0; s < 3; ++s) {
    int mts = wv * 3 + s;
    int ob = mts * 16 + g * 4;
    float bias[4];
#pragma unroll
    for (int r = 0; r < 4; ++r) bias[r] = bc[ob + r];
#pragma unroll
    for (int nt = 0; nt < 4; ++nt) {
      int n = n0 + nt * 16 + li;
      float v0 = acc[s][nt][0] + bias[0];
      float v1 = acc[s][nt][1] + bias[1];
      float v2v = acc[s][nt][2] + bias[2];
      float v3 = acc[s][nt][3] + bias[3];
      if (mts < 2) {
        v0 *= qscale; v1 *= qscale; v2v *= qscale; v3 *= qscale;
        uint2 pk; pk.x = pk2(v0, v1); pk.y = pk2(v2v, v3);
        *(uint2*)(qw + (((size_t)b * 4096) + n) * 32 + ob) = pk;
      } else if (mts < 4) {
        uint2 pk; pk.x = pk2(v0, v1); pk.y = pk2(v2v, v3);
        *(uint2*)(kw + (((size_t)b * 4096) + n) * 32 + (ob - 32)) = pk;
      } else {
        int cv = ob - 64;
        u32 w01 = (u32)__builtin_amdgcn_cvt_pk_fp8_f32(v0, v1, 0, false);
        u32 w23 = (u32)__builtin_amdgcn_cvt_pk_fp8_f32(v2v, v3, 0, false);
        size_t vb = (((size_t)b * 128 + (n >> 5)) * 128 + cv) * 32 + (n & 31);
        v2[vb]      = (u8)(w01 & 0xFF);
        v2[vb + 32] = (u8)((w01 >> 8) & 0xFF);
        v2[vb + 64] = (u8)(w23 & 0xFF);
        v2[vb + 96] = (u8)((w23 >> 8) & 0xFF);
      }
    }
  }
}

// ---------------------------------------------------------------------------
// Kernel 3: flash attention, 32x32 MFMA. Block = 8 waves (512 thr) on the
// SAME 32 q-rows; wave w handles keys [w*512,(w+1)*512). Lane layout: every
// lane owns ONE q-row (q = lane&31) -> per-lane m/l, single permlane32_swap
// for cross-pair reduce. P fp8 via cvt_pk + 2 permlane32_swap; PV fp8 32x32.
// Two-stage flash-combine (8 -> 4 -> 1) in LDS. Grid 512 blocks, 4 w/SIMD.
// ---------------------------------------------------------------------------
__global__ __launch_bounds__(512, 4) void k_attn(const u16* __restrict__ qw,
    const u16* __restrict__ kw, const u8* __restrict__ v2,
    const float* __restrict__ xp, const float* __restrict__ gamma,
    float* __restrict__ out) {
  __shared__ u32 buf[4][32][66];    // bf16-pair partial O^T
  __shared__ float lm[8][32];
  __shared__ float ll[8][32];
  int t = threadIdx.x;
  int wv = t >> 6, lane = t & 63;
  int q = lane & 31, hi = lane >> 5;
  int b = blockIdx.y;
  int q0 = blockIdx.x * 32;
  const u16* qrow = qw + (((size_t)b * 4096) + q0 + q) * 32 + hi * 8;
  bf16x8 qf0 = *(const bf16x8*)qrow;
  bf16x8 qf1 = *(const bf16x8*)(qrow + 16);
  f32x16 acc[4] = {};
  const f32x16 zz = {};
  float m = -1e30f, l = 0.f;
  const u16* kbb = kw + ((size_t)b * 4096) * 32;
  const u8* vbb = v2 + ((size_t)b * 524288);

  for (int kv0 = wv * 512; kv0 < wv * 512 + 512; kv0 += 32) {
    const u16* krow = kbb + (size_t)(kv0 + q) * 32 + hi * 8;
    bf16x8 kf0 = *(const bf16x8*)krow;
    bf16x8 kf1 = *(const bf16x8*)(krow + 16);
    f32x16 s = __builtin_amdgcn_mfma_f32_32x32x16_bf16(kf0, qf0, zz, 0, 0, 0);
    s = __builtin_amdgcn_mfma_f32_32x32x16_bf16(kf1, qf1, s, 0, 0, 0);
    // in-lane max over 16 (one q-row), then pair exchange lane<->lane+32
    float a0 = fmaxf(s[0], s[1]),  a1 = fmaxf(s[2], s[3]);
    float a2 = fmaxf(s[4], s[5]),  a3 = fmaxf(s[6], s[7]);
    float a4 = fmaxf(s[8], s[9]),  a5 = fmaxf(s[10], s[11]);
    float a6 = fmaxf(s[12], s[13]), a7 = fmaxf(s[14], s[15]);
    a0 = fmaxf(a0, a1); a2 = fmaxf(a2, a3); a4 = fmaxf(a4, a5); a6 = fmaxf(a6, a7);
    a0 = fmaxf(a0, a2); a4 = fmaxf(a4, a6);
    float mx = fmaxf(a0, a4);
    {
      union { float f; u32 u; } cv; cv.f = mx;
      u32x2 sw = __builtin_amdgcn_permlane32_swap(cv.u, cv.u, false, false);
      union { u32 u; float f; } r0, r1; r0.u = sw[0]; r1.u = sw[1];
      mx = fmaxf(r0.f, r1.f);
    }
    if (!__all(mx <= m + 8.f)) {
      float mn = fmaxf(m, mx);
      float al = fexp2(m - mn);
      l *= al;
#pragma unroll
      for (int ct = 0; ct < 4; ++ct)
#pragma unroll
        for (int r = 0; r < 16; ++r) acc[ct][r] *= al;
      m = mn;
    }
    float p[16];
#pragma unroll
    for (int r = 0; r < 16; ++r) p[r] = fexp2(s[r] - m);
    float s0 = (p[0] + p[1]) + (p[2] + p[3]);
    float s1 = (p[4] + p[5]) + (p[6] + p[7]);
    float s2 = (p[8] + p[9]) + (p[10] + p[11]);
    float s3 = (p[12] + p[13]) + (p[14] + p[15]);
    float sum = (s0 + s1) + (s2 + s3);
    {
      union { float f; u32 u; } cv; cv.f = sum;
      u32x2 sw = __builtin_amdgcn_permlane32_swap(cv.u, cv.u, false, false);
      union { u32 u; float f; } r0, r1; r0.u = sw[0]; r1.u = sw[1];
      sum = r0.f + r1.f;
    }
    l += sum;
    // pack P -> fp8 dwords (keys ascending within dword) and swap halves
    u32 dw0 = (u32)__builtin_amdgcn_cvt_pk_fp8_f32(p[0], p[1], 0, false);
    dw0 = (u32)__builtin_amdgcn_cvt_pk_fp8_f32(p[2], p[3], (int)dw0, true);
    u32 dw1 = (u32)__builtin_amdgcn_cvt_pk_fp8_f32(p[4], p[5], 0, false);
    dw1 = (u32)__builtin_amdgcn_cvt_pk_fp8_f32(p[6], p[7], (int)dw1, true);
    u32 dw2 = (u32)__builtin_amdgcn_cvt_pk_fp8_f32(p[8], p[9], 0, false);
    dw2 = (u32)__builtin_amdgcn_cvt_pk_fp8_f32(p[10], p[11], (int)dw2, true);
    u32 dw3 = (u32)__builtin_amdgcn_cvt_pk_fp8_f32(p[12], p[13], 0, false);
    dw3 = (u32)__builtin_amdgcn_cvt_pk_fp8_f32(p[14], p[15], (int)dw3, true);
    u32x2 sw0 = __builtin_amdgcn_permlane32_swap(dw0, dw1, false, false);
    u32x2 sw1 = __builtin_amdgcn_permlane32_swap(dw2, dw3, false, false);
    union { uint2 u; long long ll_; } pf0, pf1;
    pf0.u.x = sw0[0]; pf0.u.y = sw0[1];
    pf1.u.x = sw1[0]; pf1.u.y = sw1[1];
    const u8* vch = vbb + (size_t)(kv0 >> 5) * 4096 + q * 32 + hi * 8;
#pragma unroll
    for (int ct = 0; ct < 4; ++ct) {
      union { uint2 u; long long ll_; } v0, v1;
      v0.u = *(const uint2*)(vch + ct * 1024);
      v1.u = *(const uint2*)(vch + ct * 1024 + 16);
      acc[ct] = __builtin_amdgcn_mfma_f32_32x32x16_fp8_fp8(v0.ll_, pf0.ll_, acc[ct], 0, 0, 0);
      acc[ct] = __builtin_amdgcn_mfma_f32_32x32x16_fp8_fp8(v1.ll_, pf1.ll_, acc[ct], 0, 0, 0);
    }
  }

  // ---- two-stage flash-combine: 8 -> 4 -> 1 ----
  if (lane < 32) { lm[wv][q] = m; ll[wv][q] = l; }
  if (wv >= 4) {
    int w = wv - 4;
#pragma unroll
    for (int ct = 0; ct < 4; ++ct)
#pragma unroll
      for (int q4 = 0; q4 < 4; ++q4) {
        uint2 pkd;
        pkd.x = pk2(acc[ct][q4 * 4 + 0], acc[ct][q4 * 4 + 1]);
        pkd.y = pk2(acc[ct][q4 * 4 + 2], acc[ct][q4 * 4 + 3]);
        *(uint2*)&buf[w][q][16 * ct + 4 * q4 + 2 * hi] = pkd;
      }
  }
  __syncthreads();
  if (wv < 4) {
    float m2 = lm[wv + 4][q], l2 = ll[wv + 4][q];
    float mm = fmaxf(m, m2);
    float fa = fexp2(m - mm), fb = fexp2(m2 - mm);
#pragma unroll
    for (int ct = 0; ct < 4; ++ct)
#pragma unroll
      for (int q4 = 0; q4 < 4; ++q4) {
        uint2 pr = *(const uint2*)&buf[wv][q][16 * ct + 4 * q4 + 2 * hi];
        acc[ct][q4 * 4 + 0] = acc[ct][q4 * 4 + 0] * fa + bflo(pr.x) * fb;
        acc[ct][q4 * 4 + 1] = acc[ct][q4 * 4 + 1] * fa + bfhi(pr.x) * fb;
        acc[ct][q4 * 4 + 2] = acc[ct][q4 * 4 + 2] * fa + bflo(pr.y) * fb;
        acc[ct][q4 * 4 + 3] = acc[ct][q4 * 4 + 3] * fa + bfhi(pr.y) * fb;
      }
    l = l * fa + l2 * fb;
    m = mm;
  }
  __syncthreads();
  if (wv < 4 && lane < 32) { lm[wv][q] = m; ll[wv][q] = l; }
  __syncthreads();
  if (wv < 4) {
    float ms = fmaxf(fmaxf(lm[0][q], lm[1][q]), fmaxf(lm[2][q], lm[3][q]));
    float f = fexp2(m - ms);
#pragma unroll
    for (int ct = 0; ct < 4; ++ct)
#pragma unroll
      for (int q4 = 0; q4 < 4; ++q4) {
        uint2 pkd;
        pkd.x = pk2(acc[ct][q4 * 4 + 0] * f, acc[ct][q4 * 4 + 1] * f);
        pkd.y = pk2(acc[ct][q4 * 4 + 2] * f, acc[ct][q4 * 4 + 3] * f);
        *(uint2*)&buf[wv][q][16 * ct + 4 * q4 + 2 * hi] = pkd;
      }
  }
  __syncthreads();
  // epilogue: 512 threads: q-row qe = t&31, cols cg*8..cg*8+7
  int qe = t & 31, cg = t >> 5;
  float m0 = lm[0][qe], m1 = lm[1][qe], m2 = lm[2][qe], m3 = lm[3][qe];
  float ms = fmaxf(fmaxf(m0, m1), fmaxf(m2, m3));
  float ls = ll[0][qe] * fexp2(m0 - ms) + ll[1][qe] * fexp2(m1 - ms)
           + ll[2][qe] * fexp2(m2 - ms) + ll[3][qe] * fexp2(m3 - ms);
  float inv = 1.f / ls;
  float g0 = gamma[0];
  float sacc[8];
#pragma unroll
  for (int j = 0; j < 8; ++j) sacc[j] = 0.f;
#pragma unroll
  for (int w = 0; w < 4; ++w) {
    uint4 r = *(const uint4*)&buf[w][qe][cg * 4];
    sacc[0] += bflo(r.x); sacc[1] += bfhi(r.x);
    sacc[2] += bflo(r.y); sacc[3] += bfhi(r.y);
    sacc[4] += bflo(r.z); sacc[5] += bfhi(r.z);
    sacc[6] += bflo(r.w); sacc[7] += bfhi(r.w);
  }
#pragma unroll
  for (int j = 0; j < 8; ++j) {
    size_t adr = (((size_t)b * 128) + cg * 8 + j) * 4096 + q0 + qe;
    out[adr] = g0 * sacc[j] * inv + xp[adr];
  }
}

// ---------------------------------------------------------------------------
extern "C" void kernel_launch(void* const* d_in, const int* in_sizes, int n_in,
                              void* d_out, int out_size, void* d_ws, size_t ws_size,
                              hipStream_t stream) {
  const float* x     = (const float*)d_in[0];
  const float* Wq    = (const float*)d_in[1];
  const float* bq    = (const float*)d_in[2];
  const float* Wk    = (const float*)d_in[3];
  const float* bk    = (const float*)d_in[4];
  const float* Wv    = (const float*)d_in[5];
  const float* bv    = (const float*)d_in[6];
  const float* gamma = (const float*)d_in[7];
  const float* pos   = (const float*)d_in[8];
  float* out = (float*)d_out;

  char* ws = (char*)d_ws;
  float* xp  = (float*)ws;                          //  8,388,608 B  f32 [4][128][4096]
  u16* qw    = (u16*)(ws + 8388608);                //  1,048,576 B  bf16 [4][4096][32]
  u16* kw    = (u16*)(ws + 9437184);                //  1,048,576 B  bf16 [4][4096][32]
  u8*  v2    = (u8*)(ws + 10485760);                //  2,097,152 B  fp8 [4][128][128][32]
  u16* wc    = (u16*)(ws + 12582912);               //     49,152 B  bf16 [192][128]
  float* bc  = (float*)(ws + 12632064);             //        768 B  f32 [192]

  k_wcat<<<96, 256, 0, stream>>>(Wq, bq, Wk, bk, Wv, bv, wc, bc);
  k_pp<<<dim3(64, 4), 256, 0, stream>>>(x, pos, wc, bc, xp, qw, kw, v2);
  k_attn<<<dim3(128, 4), 512, 0, stream>>>(qw, kw, v2, xp, gamma, out);
}

// Round 9
// 61.640 us; speedup vs baseline: 2.7163x; 1.0774x over previous
//
#include <hip/hip_runtime.h>
#include <hip/hip_bf16.h>
#include <cstdint>
#include <cstddef>

typedef __attribute__((ext_vector_type(8))) short bf16x8;
typedef __attribute__((ext_vector_type(4))) float f32x4;
typedef __attribute__((ext_vector_type(16))) float f32x16;
typedef __attribute__((ext_vector_type(2))) unsigned int u32x2;
typedef unsigned int u32;
typedef unsigned short u16;
typedef unsigned char u8;

__device__ __forceinline__ u16 f2bf(float f) {
  union { float f; u32 u; } v; v.f = f;
  u32 r = v.u + 0x7FFFu + ((v.u >> 16) & 1u);   // round-nearest-even
  return (u16)(r >> 16);
}
__device__ __forceinline__ u32 pk2(float a, float b) {
  return (u32)f2bf(a) | ((u32)f2bf(b) << 16);
}
__device__ __forceinline__ float bfhi(u32 u) {
  union { u32 u; float f; } v; v.u = u & 0xFFFF0000u; return v.f;
}
__device__ __forceinline__ float bflo(u32 u) {
  union { u32 u; float f; } v; v.u = u << 16; return v.f;
}
__device__ __forceinline__ float fexp2(float x) {
  return __builtin_amdgcn_exp2f(x);
}

// ---------------------------------------------------------------------------
// Kernel 1: concat weights -> bf16 [192][128], bias -> f32 [192]
// ---------------------------------------------------------------------------
__global__ __launch_bounds__(256) void k_wcat(const float* __restrict__ Wq,
    const float* __restrict__ bq, const float* __restrict__ Wk,
    const float* __restrict__ bk, const float* __restrict__ Wv,
    const float* __restrict__ bv, u16* __restrict__ wc, float* __restrict__ bc) {
  int idx = blockIdx.x * 256 + threadIdx.x;
  if (idx < 24576) {
    int row = idx >> 7, col = idx & 127;
    float v = row < 32 ? Wq[row * 128 + col]
            : row < 64 ? Wk[(row - 32) * 128 + col]
                       : Wv[(row - 64) * 128 + col];
    wc[idx] = f2bf(v);
  }
  if (idx < 192)
    bc[idx] = idx < 32 ? bq[idx] : idx < 64 ? bk[idx - 32] : bv[idx - 64];
}

// ---------------------------------------------------------------------------
// Kernel 2 (fused prep+proj): bilinear PE + xp, tile kept in LDS, projection
// GEMM straight from LDS. q pre-scaled by (1/(sqrt(C)+eps))*log2(e).
// q,k -> [b][n][32] bf16; v -> fp8 e4m3 K-major [b][n/32][128][32].
// ---------------------------------------------------------------------------
__global__ __launch_bounds__(256) void k_pp(const float* __restrict__ x,
    const float* __restrict__ pos, const u16* __restrict__ wc,
    const float* __restrict__ bc, float* __restrict__ xp,
    u16* __restrict__ qw, u16* __restrict__ kw, u8* __restrict__ v2) {
  __shared__ float tf[128][66];     // xp tile [c][n]
  __shared__ u16 tb[64][136];       // bf16 [n][c] (pad to 136 for b128 align)
  int t = threadIdx.x;
  int n0 = blockIdx.x * 64;
  int b = blockIdx.y;
  int h = blockIdx.x;               // one image row per tile (W=64)
  float sy = 0.5f * (float)h - 0.25f;
  int y0 = (int)floorf(sy);
  float fy = sy - (float)y0;
  int y0c = y0 < 0 ? 0 : y0;
  int y1c = (y0 + 1 > 31) ? 31 : y0 + 1;
  {
    int cl = t >> 1, half = t & 1;
    const float* pr0 = pos + (size_t)cl * 1024 + y0c * 32;
    const float* pr1 = pos + (size_t)cl * 1024 + y1c * 32;
    size_t gbase = ((size_t)(b * 128 + cl)) * 4096 + n0;
#pragma unroll
    for (int u = 0; u < 8; ++u) {
      int nl = half * 32 + u * 4;
      float4 xv = *(const float4*)(x + gbase + nl);
      float vals[4] = {xv.x, xv.y, xv.z, xv.w};
#pragma unroll
      for (int j = 0; j < 4; ++j) {
        int w = nl + j;
        float sx = 0.5f * (float)w - 0.25f;
        int xi = (int)floorf(sx);
        float fx = sx - (float)xi;
        int x0c = xi < 0 ? 0 : xi;
        int x1c = (xi + 1 > 31) ? 31 : xi + 1;
        float top = (1.f - fx) * pr0[x0c] + fx * pr0[x1c];
        float bot = (1.f - fx) * pr1[x0c] + fx * pr1[x1c];
        float pe = (1.f - fy) * top + fy * bot;
        float xe = vals[j] + 0.025f * pe;   // 0.25 * 0.1
        vals[j] = xe;
        tf[cl][nl + j] = xe;
      }
      float4 st = {vals[0], vals[1], vals[2], vals[3]};
      *(float4*)(xp + gbase + nl) = st;
    }
  }
  __syncthreads();
  {  // transpose-pack f32 [c][n] -> bf16 [n][c]
    int nl = t & 63, qr = t >> 6;
    u32* tbw = (u32*)&tb[0][0];
#pragma unroll
    for (int hc = 0; hc < 2; ++hc) {
      int cbase = qr * 16 + hc * 64;
#pragma unroll
      for (int p = 0; p < 8; ++p)
        tbw[nl * 68 + cbase / 2 + p] =
            pk2(tf[cbase + 2 * p][nl], tf[cbase + 2 * p + 1][nl]);
    }
  }
  __syncthreads();
  // projection: wave wv -> m-tiles wv*3..wv*3+2 of Wcat(192x128)
  int wv = t >> 6, lane = t & 63, li = lane & 15, g = lane >> 4;
  const float qscale = 0.088388347648318447f * 1.4426950408889634f;
  f32x4 acc[3][4];
#pragma unroll
  for (int s = 0; s < 3; ++s)
#pragma unroll
    for (int nt = 0; nt < 4; ++nt) acc[s][nt] = (f32x4){0.f, 0.f, 0.f, 0.f};
#pragma unroll
  for (int kc = 0; kc < 4; ++kc) {
    bf16x8 af[3], bfr[4];
#pragma unroll
    for (int s = 0; s < 3; ++s)
      af[s] = *(const bf16x8*)(wc + ((wv * 3 + s) * 16 + li) * 128 + kc * 32 + g * 8);
#pragma unroll
    for (int nt = 0; nt < 4; ++nt)
      bfr[nt] = *(const bf16x8*)&tb[nt * 16 + li][kc * 32 + g * 8];
#pragma unroll
    for (int s = 0; s < 3; ++s)
#pragma unroll
      for (int nt = 0; nt < 4; ++nt)
        acc[s][nt] = __builtin_amdgcn_mfma_f32_16x16x32_bf16(af[s], bfr[nt], acc[s][nt], 0, 0, 0);
  }
#pragma unroll
  for (int s = 0; s < 3; ++s) {
    int mts = wv * 3 + s;
    int ob = mts * 16 + g * 4;
    float bias[4];
#pragma unroll
    for (int r = 0; r < 4; ++r) bias[r] = bc[ob + r];
#pragma unroll
    for (int nt = 0; nt < 4; ++nt) {
      int n = n0 + nt * 16 + li;
      float v0 = acc[s][nt][0] + bias[0];
      float v1 = acc[s][nt][1] + bias[1];
      float v2v = acc[s][nt][2] + bias[2];
      float v3 = acc[s][nt][3] + bias[3];
      if (mts < 2) {
        v0 *= qscale; v1 *= qscale; v2v *= qscale; v3 *= qscale;
        uint2 pk; pk.x = pk2(v0, v1); pk.y = pk2(v2v, v3);
        *(uint2*)(qw + (((size_t)b * 4096) + n) * 32 + ob) = pk;
      } else if (mts < 4) {
        uint2 pk; pk.x = pk2(v0, v1); pk.y = pk2(v2v, v3);
        *(uint2*)(kw + (((size_t)b * 4096) + n) * 32 + (ob - 32)) = pk;
      } else {
        int cv = ob - 64;
        u32 w01 = (u32)__builtin_amdgcn_cvt_pk_fp8_f32(v0, v1, 0, false);
        u32 w23 = (u32)__builtin_amdgcn_cvt_pk_fp8_f32(v2v, v3, 0, false);
        size_t vb = (((size_t)b * 128 + (n >> 5)) * 128 + cv) * 32 + (n & 31);
        v2[vb]      = (u8)(w01 & 0xFF);
        v2[vb + 32] = (u8)((w01 >> 8) & 0xFF);
        v2[vb + 64] = (u8)(w23 & 0xFF);
        v2[vb + 96] = (u8)((w23 >> 8) & 0xFF);
      }
    }
  }
}

// ---------------------------------------------------------------------------
// Kernel 3: flash attention, 32x32 MFMA, 2 q-subtiles per wave + prefetch.
// Block = 8 waves (512 thr) on the SAME 64 q-rows (subtiles A=0..31, B=32..63);
// wave w handles keys [w*512,(w+1)*512). V loads issued at top of iter
// (hidden under QK+softmax); K double-buffered (next tile prefetched).
// Per-lane m/l (q = lane&31); P fp8 via cvt_pk + permlane32_swap.
// Two combine passes (A then B) reusing one 34KB LDS buffer.
// Grid 256 blocks = 1 block/CU, 2 waves/SIMD.
// ---------------------------------------------------------------------------
__global__ __launch_bounds__(512, 2) void k_attn(const u16* __restrict__ qw,
    const u16* __restrict__ kw, const u8* __restrict__ v2,
    const float* __restrict__ xp, const float* __restrict__ gamma,
    float* __restrict__ out) {
  __shared__ u32 buf[4][32][66];    // bf16-pair partial O^T
  __shared__ float lm[8][32];
  __shared__ float ll[8][32];
  int t = threadIdx.x;
  int wv = t >> 6, lane = t & 63;
  int q = lane & 31, hi = lane >> 5;
  int b = blockIdx.y;
  int q0 = blockIdx.x * 64;
  const u16* qbase = qw + (((size_t)b * 4096) + q0) * 32 + hi * 8;
  bf16x8 qA0 = *(const bf16x8*)(qbase + (size_t)q * 32);
  bf16x8 qA1 = *(const bf16x8*)(qbase + (size_t)q * 32 + 16);
  bf16x8 qB0 = *(const bf16x8*)(qbase + (size_t)(32 + q) * 32);
  bf16x8 qB1 = *(const bf16x8*)(qbase + (size_t)(32 + q) * 32 + 16);
  f32x16 accA[4] = {}, accB[4] = {};
  const f32x16 zz = {};
  float mA = -1e30f, lA = 0.f, mB = -1e30f, lB = 0.f;
  const u16* kbb = kw + ((size_t)b * 4096) * 32;
  const u8* vbb = v2 + (size_t)b * 524288;
  int kv_beg = wv * 512;
  // preload K tile 0
  const u16* kr0 = kbb + (size_t)(kv_beg + q) * 32 + hi * 8;
  bf16x8 kc0 = *(const bf16x8*)kr0;
  bf16x8 kc1 = *(const bf16x8*)(kr0 + 16);

  for (int it = 0; it < 16; ++it) {
    int kv0 = kv_beg + it * 32;
    // issue current V loads first (consumed after QK+softmax ~200cyc later)
    const u8* vch = vbb + (size_t)(kv0 >> 5) * 4096 + q * 32 + hi * 8;
    uint2 vr[8];
#pragma unroll
    for (int ct = 0; ct < 4; ++ct) {
      vr[2 * ct]     = *(const uint2*)(vch + ct * 1024);
      vr[2 * ct + 1] = *(const uint2*)(vch + ct * 1024 + 16);
    }
    // prefetch next K tile
    bf16x8 kn0 = kc0, kn1 = kc1;
    if (it < 15) {
      const u16* krn = kbb + (size_t)(kv0 + 32 + q) * 32 + hi * 8;
      kn0 = *(const bf16x8*)krn;
      kn1 = *(const bf16x8*)(krn + 16);
    }
    // QK^T for both subtiles
    f32x16 sA = __builtin_amdgcn_mfma_f32_32x32x16_bf16(kc0, qA0, zz, 0, 0, 0);
    sA = __builtin_amdgcn_mfma_f32_32x32x16_bf16(kc1, qA1, sA, 0, 0, 0);
    f32x16 sB = __builtin_amdgcn_mfma_f32_32x32x16_bf16(kc0, qB0, zz, 0, 0, 0);
    sB = __builtin_amdgcn_mfma_f32_32x32x16_bf16(kc1, qB1, sB, 0, 0, 0);
    // tile maxes
    float xa0 = fmaxf(fmaxf(sA[0], sA[1]), fmaxf(sA[2], sA[3]));
    float xa1 = fmaxf(fmaxf(sA[4], sA[5]), fmaxf(sA[6], sA[7]));
    float xa2 = fmaxf(fmaxf(sA[8], sA[9]), fmaxf(sA[10], sA[11]));
    float xa3 = fmaxf(fmaxf(sA[12], sA[13]), fmaxf(sA[14], sA[15]));
    float mxA = fmaxf(fmaxf(xa0, xa1), fmaxf(xa2, xa3));
    float xb0 = fmaxf(fmaxf(sB[0], sB[1]), fmaxf(sB[2], sB[3]));
    float xb1 = fmaxf(fmaxf(sB[4], sB[5]), fmaxf(sB[6], sB[7]));
    float xb2 = fmaxf(fmaxf(sB[8], sB[9]), fmaxf(sB[10], sB[11]));
    float xb3 = fmaxf(fmaxf(sB[12], sB[13]), fmaxf(sB[14], sB[15]));
    float mxB = fmaxf(fmaxf(xb0, xb1), fmaxf(xb2, xb3));
    {
      union { float f; u32 u; } ca, cb;
      ca.f = mxA; cb.f = mxB;
      u32x2 swa = __builtin_amdgcn_permlane32_swap(ca.u, ca.u, false, false);
      u32x2 swb = __builtin_amdgcn_permlane32_swap(cb.u, cb.u, false, false);
      union { u32 u; float f; } r0, r1;
      r0.u = swa[0]; r1.u = swa[1]; mxA = fmaxf(r0.f, r1.f);
      r0.u = swb[0]; r1.u = swb[1]; mxB = fmaxf(r0.f, r1.f);
    }
    bool ok = (mxA <= mA + 8.f) && (mxB <= mB + 8.f);
    if (!__all(ok)) {
      float mnA = fmaxf(mA, mxA), mnB = fmaxf(mB, mxB);
      float aA = fexp2(mA - mnA), aB = fexp2(mB - mnB);
      lA *= aA; lB *= aB;
#pragma unroll
      for (int ct = 0; ct < 4; ++ct)
#pragma unroll
        for (int r = 0; r < 16; ++r) {
          accA[ct][r] *= aA;
          accB[ct][r] *= aB;
        }
      mA = mnA; mB = mnB;
    }
    // ---- subtile A: P, pack, PV ----
    {
      float p[16];
#pragma unroll
      for (int r = 0; r < 16; ++r) p[r] = fexp2(sA[r] - mA);
      float s0 = (p[0] + p[1]) + (p[2] + p[3]);
      float s1 = (p[4] + p[5]) + (p[6] + p[7]);
      float s2 = (p[8] + p[9]) + (p[10] + p[11]);
      float s3 = (p[12] + p[13]) + (p[14] + p[15]);
      float sum = (s0 + s1) + (s2 + s3);
      union { float f; u32 u; } cv; cv.f = sum;
      u32x2 sw = __builtin_amdgcn_permlane32_swap(cv.u, cv.u, false, false);
      union { u32 u; float f; } r0, r1; r0.u = sw[0]; r1.u = sw[1];
      lA += r0.f + r1.f;
      u32 dw0 = (u32)__builtin_amdgcn_cvt_pk_fp8_f32(p[0], p[1], 0, false);
      dw0 = (u32)__builtin_amdgcn_cvt_pk_fp8_f32(p[2], p[3], (int)dw0, true);
      u32 dw1 = (u32)__builtin_amdgcn_cvt_pk_fp8_f32(p[4], p[5], 0, false);
      dw1 = (u32)__builtin_amdgcn_cvt_pk_fp8_f32(p[6], p[7], (int)dw1, true);
      u32 dw2 = (u32)__builtin_amdgcn_cvt_pk_fp8_f32(p[8], p[9], 0, false);
      dw2 = (u32)__builtin_amdgcn_cvt_pk_fp8_f32(p[10], p[11], (int)dw2, true);
      u32 dw3 = (u32)__builtin_amdgcn_cvt_pk_fp8_f32(p[12], p[13], 0, false);
      dw3 = (u32)__builtin_amdgcn_cvt_pk_fp8_f32(p[14], p[15], (int)dw3, true);
      u32x2 sw0 = __builtin_amdgcn_permlane32_swap(dw0, dw1, false, false);
      u32x2 sw1 = __builtin_amdgcn_permlane32_swap(dw2, dw3, false, false);
      union { uint2 u; long long l_; } pf0, pf1;
      pf0.u.x = sw0[0]; pf0.u.y = sw0[1];
      pf1.u.x = sw1[0]; pf1.u.y = sw1[1];
#pragma unroll
      for (int ct = 0; ct < 4; ++ct) {
        union { uint2 u; long long l_; } v0u, v1u;
        v0u.u = vr[2 * ct]; v1u.u = vr[2 * ct + 1];
        accA[ct] = __builtin_amdgcn_mfma_f32_32x32x16_fp8_fp8(v0u.l_, pf0.l_, accA[ct], 0, 0, 0);
        accA[ct] = __builtin_amdgcn_mfma_f32_32x32x16_fp8_fp8(v1u.l_, pf1.l_, accA[ct], 0, 0, 0);
      }
    }
    // ---- subtile B: P, pack, PV ----
    {
      float p[16];
#pragma unroll
      for (int r = 0; r < 16; ++r) p[r] = fexp2(sB[r] - mB);
      float s0 = (p[0] + p[1]) + (p[2] + p[3]);
      float s1 = (p[4] + p[5]) + (p[6] + p[7]);
      float s2 = (p[8] + p[9]) + (p[10] + p[11]);
      float s3 = (p[12] + p[13]) + (p[14] + p[15]);
      float sum = (s0 + s1) + (s2 + s3);
      union { float f; u32 u; } cv; cv.f = sum;
      u32x2 sw = __builtin_amdgcn_permlane32_swap(cv.u, cv.u, false, false);
      union { u32 u; float f; } r0, r1; r0.u = sw[0]; r1.u = sw[1];
      lB += r0.f + r1.f;
      u32 dw0 = (u32)__builtin_amdgcn_cvt_pk_fp8_f32(p[0], p[1], 0, false);
      dw0 = (u32)__builtin_amdgcn_cvt_pk_fp8_f32(p[2], p[3], (int)dw0, true);
      u32 dw1 = (u32)__builtin_amdgcn_cvt_pk_fp8_f32(p[4], p[5], 0, false);
      dw1 = (u32)__builtin_amdgcn_cvt_pk_fp8_f32(p[6], p[7], (int)dw1, true);
      u32 dw2 = (u32)__builtin_amdgcn_cvt_pk_fp8_f32(p[8], p[9], 0, false);
      dw2 = (u32)__builtin_amdgcn_cvt_pk_fp8_f32(p[10], p[11], (int)dw2, true);
      u32 dw3 = (u32)__builtin_amdgcn_cvt_pk_fp8_f32(p[12], p[13], 0, false);
      dw3 = (u32)__builtin_amdgcn_cvt_pk_fp8_f32(p[14], p[15], (int)dw3, true);
      u32x2 sw0 = __builtin_amdgcn_permlane32_swap(dw0, dw1, false, false);
      u32x2 sw1 = __builtin_amdgcn_permlane32_swap(dw2, dw3, false, false);
      union { uint2 u; long long l_; } pf0, pf1;
      pf0.u.x = sw0[0]; pf0.u.y = sw0[1];
      pf1.u.x = sw1[0]; pf1.u.y = sw1[1];
#pragma unroll
      for (int ct = 0; ct < 4; ++ct) {
        union { uint2 u; long long l_; } v0u, v1u;
        v0u.u = vr[2 * ct]; v1u.u = vr[2 * ct + 1];
        accB[ct] = __builtin_amdgcn_mfma_f32_32x32x16_fp8_fp8(v0u.l_, pf0.l_, accB[ct], 0, 0, 0);
        accB[ct] = __builtin_amdgcn_mfma_f32_32x32x16_fp8_fp8(v1u.l_, pf1.l_, accB[ct], 0, 0, 0);
      }
    }
    kc0 = kn0; kc1 = kn1;
  }

  float g0 = gamma[0];
  // ---- combine pass macro: 8 -> 4 -> 1 waves, then epilogue ----
#define COMBINE_PASS(ACC, MV, LV, QOFF)                                       \
  __syncthreads();                                                            \
  if (lane < 32) { lm[wv][q] = MV; ll[wv][q] = LV; }                          \
  if (wv >= 4) {                                                              \
    int w = wv - 4;                                                           \
    _Pragma("unroll")                                                         \
    for (int ct = 0; ct < 4; ++ct)                                            \
      _Pragma("unroll")                                                       \
      for (int q4 = 0; q4 < 4; ++q4) {                                        \
        uint2 pkd;                                                            \
        pkd.x = pk2(ACC[ct][q4 * 4 + 0], ACC[ct][q4 * 4 + 1]);                \
        pkd.y = pk2(ACC[ct][q4 * 4 + 2], ACC[ct][q4 * 4 + 3]);                \
        *(uint2*)&buf[w][q][16 * ct + 4 * q4 + 2 * hi] = pkd;                 \
      }                                                                       \
  }                                                                           \
  __syncthreads();                                                            \
  if (wv < 4) {                                                               \
    float m2 = lm[wv + 4][q], l2 = ll[wv + 4][q];                             \
    float mm = fmaxf(MV, m2);                                                 \
    float fa = fexp2(MV - mm), fb = fexp2(m2 - mm);                           \
    _Pragma("unroll")                                                         \
    for (int ct = 0; ct < 4; ++ct)                                            \
      _Pragma("unroll")                                                       \
      for (int q4 = 0; q4 < 4; ++q4) {                                        \
        uint2 pr = *(const uint2*)&buf[wv][q][16 * ct + 4 * q4 + 2 * hi];     \
        ACC[ct][q4 * 4 + 0] = ACC[ct][q4 * 4 + 0] * fa + bflo(pr.x) * fb;     \
        ACC[ct][q4 * 4 + 1] = ACC[ct][q4 * 4 + 1] * fa + bfhi(pr.x) * fb;     \
        ACC[ct][q4 * 4 + 2] = ACC[ct][q4 * 4 + 2] * fa + bflo(pr.y) * fb;     \
        ACC[ct][q4 * 4 + 3] = ACC[ct][q4 * 4 + 3] * fa + bfhi(pr.y) * fb;     \
      }                                                                       \
    LV = LV * fa + l2 * fb;                                                   \
    MV = mm;                                                                  \
  }                                                                           \
  __syncthreads();                                                            \
  if (wv < 4 && lane < 32) { lm[wv][q] = MV; ll[wv][q] = LV; }                \
  __syncthreads();                                                            \
  if (wv < 4) {                                                               \
    float ms = fmaxf(fmaxf(lm[0][q], lm[1][q]), fmaxf(lm[2][q], lm[3][q]));   \
    float f = fexp2(MV - ms);                                                 \
    _Pragma("unroll")                                                         \
    for (int ct = 0; ct < 4; ++ct)                                            \
      _Pragma("unroll")                                                       \
      for (int q4 = 0; q4 < 4; ++q4) {                                        \
        uint2 pkd;                                                            \
        pkd.x = pk2(ACC[ct][q4 * 4 + 0] * f, ACC[ct][q4 * 4 + 1] * f);        \
        pkd.y = pk2(ACC[ct][q4 * 4 + 2] * f, ACC[ct][q4 * 4 + 3] * f);        \
        *(uint2*)&buf[wv][q][16 * ct + 4 * q4 + 2 * hi] = pkd;                \
      }                                                                       \
  }                                                                           \
  __syncthreads();                                                            \
  {                                                                           \
    int qe = t & 31, cg = t >> 5;                                             \
    float m0 = lm[0][qe], m1 = lm[1][qe], m2 = lm[2][qe], m3 = lm[3][qe];     \
    float ms = fmaxf(fmaxf(m0, m1), fmaxf(m2, m3));                           \
    float ls = ll[0][qe] * fexp2(m0 - ms) + ll[1][qe] * fexp2(m1 - ms)        \
             + ll[2][qe] * fexp2(m2 - ms) + ll[3][qe] * fexp2(m3 - ms);       \
    float inv = 1.f / ls;                                                     \
    float sacc[8];                                                            \
    _Pragma("unroll")                                                         \
    for (int j = 0; j < 8; ++j) sacc[j] = 0.f;                                \
    _Pragma("unroll")                                                         \
    for (int w = 0; w < 4; ++w) {                                             \
      uint4 r = *(const uint4*)&buf[w][qe][cg * 4];                           \
      sacc[0] += bflo(r.x); sacc[1] += bfhi(r.x);                             \
      sacc[2] += bflo(r.y); sacc[3] += bfhi(r.y);                             \
      sacc[4] += bflo(r.z); sacc[5] += bfhi(r.z);                             \
      sacc[6] += bflo(r.w); sacc[7] += bfhi(r.w);                             \
    }                                                                         \
    _Pragma("unroll")                                                         \
    for (int j = 0; j < 8; ++j) {                                             \
      size_t adr = (((size_t)b * 128) + cg * 8 + j) * 4096 + q0 + (QOFF) + qe;\
      out[adr] = g0 * sacc[j] * inv + xp[adr];                                \
    }                                                                         \
  }

  COMBINE_PASS(accA, mA, lA, 0)
  COMBINE_PASS(accB, mB, lB, 32)
#undef COMBINE_PASS
}

// ---------------------------------------------------------------------------
extern "C" void kernel_launch(void* const* d_in, const int* in_sizes, int n_in,
                              void* d_out, int out_size, void* d_ws, size_t ws_size,
                              hipStream_t stream) {
  const float* x     = (const float*)d_in[0];
  const float* Wq    = (const float*)d_in[1];
  const float* bq    = (const float*)d_in[2];
  const float* Wk    = (const float*)d_in[3];
  const float* bk    = (const float*)d_in[4];
  const float* Wv    = (const float*)d_in[5];
  const float* bv    = (const float*)d_in[6];
  const float* gamma = (const float*)d_in[7];
  const float* pos   = (const float*)d_in[8];
  float* out = (float*)d_out;

  char* ws = (char*)d_ws;
  float* xp  = (float*)ws;                          //  8,388,608 B  f32 [4][128][4096]
  u16* qw    = (u16*)(ws + 8388608);                //  1,048,576 B  bf16 [4][4096][32]
  u16* kw    = (u16*)(ws + 9437184);                //  1,048,576 B  bf16 [4][4096][32]
  u8*  v2    = (u8*)(ws + 10485760);                //  2,097,152 B  fp8 [4][128][128][32]
  u16* wc    = (u16*)(ws + 12582912);               //     49,152 B  bf16 [192][128]
  float* bc  = (float*)(ws + 12632064);             //        768 B  f32 [192]

  k_wcat<<<96, 256, 0, stream>>>(Wq, bq, Wk, bk, Wv, bv, wc, bc);
  k_pp<<<dim3(64, 4), 256, 0, stream>>>(x, pos, wc, bc, xp, qw, kw, v2);
  k_attn<<<dim3(64, 4), 512, 0, stream>>>(qw, kw, v2, xp, gamma, out);
}

// Round 10
// 43.914 us; speedup vs baseline: 3.8128x; 1.4037x over previous
//
#include <hip/hip_runtime.h>
#include <hip/hip_bf16.h>
#include <cstdint>
#include <cstddef>

typedef __attribute__((ext_vector_type(8))) short bf16x8;
typedef __attribute__((ext_vector_type(4))) float f32x4;
typedef __attribute__((ext_vector_type(16))) float f32x16;
typedef __attribute__((ext_vector_type(2))) unsigned int u32x2;
typedef unsigned int u32;
typedef unsigned short u16;
typedef unsigned char u8;

__device__ __forceinline__ u16 f2bf(float f) {
  union { float f; u32 u; } v; v.f = f;
  u32 r = v.u + 0x7FFFu + ((v.u >> 16) & 1u);   // round-nearest-even
  return (u16)(r >> 16);
}
__device__ __forceinline__ u32 pk2(float a, float b) {
  return (u32)f2bf(a) | ((u32)f2bf(b) << 16);
}
__device__ __forceinline__ float bfhi(u32 u) {
  union { u32 u; float f; } v; v.u = u & 0xFFFF0000u; return v.f;
}
__device__ __forceinline__ float bflo(u32 u) {
  union { u32 u; float f; } v; v.u = u << 16; return v.f;
}
__device__ __forceinline__ float fexp2(float x) {
  return __builtin_amdgcn_exp2f(x);
}

// ---------------------------------------------------------------------------
// Kernel 1 (fused prep + proj, weights read直接 from global):
// bilinear PE (exact 2x-upsample: fixed 0.25/0.75 taps) + xp = x + 0.025*pe;
// tile kept in LDS; projection GEMM from LDS with on-the-fly bf16 weights.
// q pre-scaled by (1/(sqrt(C)+eps))*log2(e).
// q,k -> [b][n][32] bf16; v -> fp8 e4m3 K-major [b][n/32][128][32].
// 512 threads, grid 64x4.
// ---------------------------------------------------------------------------
struct ProjArgs {
  const u16* tbrow;   // unused placeholder
};

__device__ __forceinline__ void proj_tile(int mts, int li, int g,
    const u16* tb, int tb_stride_u16, int n0, int b,
    const float* Wq, const float* bq, const float* Wk, const float* bk,
    const float* Wv, const float* bv,
    u16* qw, u16* kw, u8* v2) {
  const float qscale = 0.088388347648318447f * 1.4426950408889634f;
  // weight row pointer for this lane's A-fragment rows
  int row = mts * 16 + li;
  const float* wsrc = row < 32 ? Wq + (size_t)row * 128
                    : row < 64 ? Wk + (size_t)(row - 32) * 128
                               : Wv + (size_t)(row - 64) * 128;
  int ob = mts * 16 + g * 4;
  const float* bsrc = ob < 32 ? bq + ob : ob < 64 ? bk + (ob - 32) : bv + (ob - 64);
  f32x4 acc[4];
#pragma unroll
  for (int nt = 0; nt < 4; ++nt) acc[nt] = (f32x4){0.f, 0.f, 0.f, 0.f};
#pragma unroll
  for (int kc = 0; kc < 4; ++kc) {
    // A-frag: 8 f32 -> bf16x8
    float4 wa = *(const float4*)(wsrc + kc * 32 + g * 8);
    float4 wb = *(const float4*)(wsrc + kc * 32 + g * 8 + 4);
    union { u32 u[4]; bf16x8 v; } af;
    af.u[0] = pk2(wa.x, wa.y); af.u[1] = pk2(wa.z, wa.w);
    af.u[2] = pk2(wb.x, wb.y); af.u[3] = pk2(wb.z, wb.w);
    bf16x8 bfr[4];
#pragma unroll
    for (int nt = 0; nt < 4; ++nt)
      bfr[nt] = *(const bf16x8*)(tb + (size_t)(nt * 16 + li) * tb_stride_u16 + kc * 32 + g * 8);
#pragma unroll
    for (int nt = 0; nt < 4; ++nt)
      acc[nt] = __builtin_amdgcn_mfma_f32_16x16x32_bf16(af.v, bfr[nt], acc[nt], 0, 0, 0);
  }
  float bias[4];
#pragma unroll
  for (int r = 0; r < 4; ++r) bias[r] = bsrc[r];
#pragma unroll
  for (int nt = 0; nt < 4; ++nt) {
    int n = n0 + nt * 16 + li;
    float v0 = acc[nt][0] + bias[0];
    float v1 = acc[nt][1] + bias[1];
    float v2v = acc[nt][2] + bias[2];
    float v3 = acc[nt][3] + bias[3];
    if (mts < 2) {
      v0 *= qscale; v1 *= qscale; v2v *= qscale; v3 *= qscale;
      uint2 pk; pk.x = pk2(v0, v1); pk.y = pk2(v2v, v3);
      *(uint2*)(qw + (((size_t)b * 4096) + n) * 32 + ob) = pk;
    } else if (mts < 4) {
      uint2 pk; pk.x = pk2(v0, v1); pk.y = pk2(v2v, v3);
      *(uint2*)(kw + (((size_t)b * 4096) + n) * 32 + (ob - 32)) = pk;
    } else {
      int cv = ob - 64;
      u32 w01 = (u32)__builtin_amdgcn_cvt_pk_fp8_f32(v0, v1, 0, false);
      u32 w23 = (u32)__builtin_amdgcn_cvt_pk_fp8_f32(v2v, v3, 0, false);
      size_t vb = (((size_t)b * 128 + (n >> 5)) * 128 + cv) * 32 + (n & 31);
      v2[vb]      = (u8)(w01 & 0xFF);
      v2[vb + 32] = (u8)((w01 >> 8) & 0xFF);
      v2[vb + 64] = (u8)(w23 & 0xFF);
      v2[vb + 96] = (u8)((w23 >> 8) & 0xFF);
    }
  }
}

__global__ __launch_bounds__(512) void k_pp(const float* __restrict__ x,
    const float* __restrict__ pos,
    const float* __restrict__ Wq, const float* __restrict__ bq,
    const float* __restrict__ Wk, const float* __restrict__ bk,
    const float* __restrict__ Wv, const float* __restrict__ bv,
    float* __restrict__ xp,
    u16* __restrict__ qw, u16* __restrict__ kw, u8* __restrict__ v2) {
  __shared__ float tf[128][66];     // xp tile [c][n]  (33.8 KB)
  __shared__ u16 tb[64][136];       // bf16 [n][c]     (17.4 KB)
  int t = threadIdx.x;
  int n0 = blockIdx.x * 64;
  int b = blockIdx.y;
  int h = blockIdx.x;               // one image row per tile (W=64)
  // vertical taps: h=2j -> rows (j-1, j) w (0.25,0.75); h=2j+1 -> (j, j+1) w (0.75,0.25)
  int hj = h >> 1;
  int ya, yb; float wa, wb;
  if ((h & 1) == 0) { ya = hj - 1 < 0 ? 0 : hj - 1; yb = hj; wa = 0.25f; wb = 0.75f; }
  else             { ya = hj; yb = hj + 1 > 31 ? 31 : hj + 1; wa = 0.75f; wb = 0.25f; }
  {
    int cl = t >> 2, q4 = t & 3;
    int w0 = q4 * 16;
    const float* pr0 = pos + (size_t)cl * 1024 + ya * 32;
    const float* pr1 = pos + (size_t)cl * 1024 + yb * 32;
    // row-interp r[j] for source cols i0-1 .. i0+8 (clamped)
    int i0 = q4 * 8;
    float rr[10];
#pragma unroll
    for (int j = 0; j < 10; ++j) {
      int idx = i0 - 1 + j;
      idx = idx < 0 ? 0 : (idx > 31 ? 31 : idx);
      rr[j] = wa * pr0[idx] + wb * pr1[idx];
    }
    size_t gbase = ((size_t)(b * 128 + cl)) * 4096 + h * 64 + w0;
#pragma unroll
    for (int u = 0; u < 4; ++u) {
      float4 xv = *(const float4*)(x + gbase + u * 4);
      float vals[4] = {xv.x, xv.y, xv.z, xv.w};
#pragma unroll
      for (int j = 0; j < 4; ++j) {
        int e = u * 4 + j;                 // 0..15, parity == w parity
        int li = (e >> 1) + 1;             // index of source col i in rr[]
        float pe = (e & 1) == 0 ? 0.25f * rr[li - 1] + 0.75f * rr[li]
                                : 0.75f * rr[li] + 0.25f * rr[li + 1];
        float xe = vals[j] + 0.025f * pe;  // 0.25 * 0.1
        vals[j] = xe;
        tf[cl][w0 + e] = xe;
      }
      float4 st = {vals[0], vals[1], vals[2], vals[3]};
      *(float4*)(xp + gbase + u * 4) = st;
    }
  }
  __syncthreads();
  {  // transpose-pack f32 [c][n] -> bf16 [n][c]; 512 thr: 8 pairs each
    int nl = t & 63, qr = t >> 6;
    u32* tbw = (u32*)&tb[0][0];
#pragma unroll
    for (int p = 0; p < 8; ++p)
      tbw[nl * 68 + qr * 8 + p] =
          pk2(tf[qr * 16 + 2 * p][nl], tf[qr * 16 + 2 * p + 1][nl]);
  }
  __syncthreads();
  // projection: 8 waves over 12 m-tiles (wave w: tile w; waves 0-3 also tile 8+w)
  int wv = t >> 6, lane = t & 63, li = lane & 15, g = lane >> 4;
  proj_tile(wv, li, g, &tb[0][0], 136, n0, b, Wq, bq, Wk, bk, Wv, bv, qw, kw, v2);
  if (wv < 4)
    proj_tile(8 + wv, li, g, &tb[0][0], 136, n0, b, Wq, bq, Wk, bk, Wv, bv, qw, kw, v2);
}

// ---------------------------------------------------------------------------
// Kernel 2: flash attention, 32x32 MFMA, 2 q-subtiles per wave + prefetch.
// Block = 8 waves (512 thr) on the SAME 64 q-rows (subtiles A=0..31, B=32..63);
// wave w handles keys [w*512,(w+1)*512). V loads issued at top of iter
// (hidden under QK+softmax); K registers rotated: reloaded right after last
// use, completing during softmax+PV. Per-lane m/l (q = lane&31); P fp8 via
// cvt_pk + permlane32_swap. Two combine passes reuse one 34KB LDS buffer.
// Grid 256 blocks = 1 block/CU, 2 waves/SIMD.
// ---------------------------------------------------------------------------
__global__ __launch_bounds__(512, 2) void k_attn(const u16* __restrict__ qw,
    const u16* __restrict__ kw, const u8* __restrict__ v2,
    const float* __restrict__ xp, const float* __restrict__ gamma,
    float* __restrict__ out) {
  __shared__ u32 buf[4][32][66];    // bf16-pair partial O^T
  __shared__ float lm[8][32];
  __shared__ float ll[8][32];
  int t = threadIdx.x;
  int wv = t >> 6, lane = t & 63;
  int q = lane & 31, hi = lane >> 5;
  int b = blockIdx.y;
  int q0 = blockIdx.x * 64;
  const u16* qbase = qw + (((size_t)b * 4096) + q0) * 32 + hi * 8;
  bf16x8 qA0 = *(const bf16x8*)(qbase + (size_t)q * 32);
  bf16x8 qA1 = *(const bf16x8*)(qbase + (size_t)q * 32 + 16);
  bf16x8 qB0 = *(const bf16x8*)(qbase + (size_t)(32 + q) * 32);
  bf16x8 qB1 = *(const bf16x8*)(qbase + (size_t)(32 + q) * 32 + 16);
  f32x16 accA[4] = {}, accB[4] = {};
  const f32x16 zz = {};
  float mA = -1e30f, lA = 0.f, mB = -1e30f, lB = 0.f;
  const u16* kbb = kw + ((size_t)b * 4096) * 32;
  const u8* vbb = v2 + (size_t)b * 524288;
  int kv_beg = wv * 512;
  // preload K tile 0
  const u16* kr0 = kbb + (size_t)(kv_beg + q) * 32 + hi * 8;
  bf16x8 kc0 = *(const bf16x8*)kr0;
  bf16x8 kc1 = *(const bf16x8*)(kr0 + 16);

  for (int it = 0; it < 16; ++it) {
    int kv0 = kv_beg + it * 32;
    // issue current V loads first (consumed after QK+softmax ~200cyc later)
    const u8* vch = vbb + (size_t)(kv0 >> 5) * 4096 + q * 32 + hi * 8;
    uint2 vr[8];
#pragma unroll
    for (int ct = 0; ct < 4; ++ct) {
      vr[2 * ct]     = *(const uint2*)(vch + ct * 1024);
      vr[2 * ct + 1] = *(const uint2*)(vch + ct * 1024 + 16);
    }
    // QK^T for both subtiles (last use of kc)
    f32x16 sA = __builtin_amdgcn_mfma_f32_32x32x16_bf16(kc0, qA0, zz, 0, 0, 0);
    sA = __builtin_amdgcn_mfma_f32_32x32x16_bf16(kc1, qA1, sA, 0, 0, 0);
    f32x16 sB = __builtin_amdgcn_mfma_f32_32x32x16_bf16(kc0, qB0, zz, 0, 0, 0);
    sB = __builtin_amdgcn_mfma_f32_32x32x16_bf16(kc1, qB1, sB, 0, 0, 0);
    // rotate K: reload same registers for next iter; completes during softmax+PV
    if (it < 15) {
      const u16* krn = kbb + (size_t)(kv0 + 32 + q) * 32 + hi * 8;
      kc0 = *(const bf16x8*)krn;
      kc1 = *(const bf16x8*)(krn + 16);
    }
    // tile maxes
    float xa0 = fmaxf(fmaxf(sA[0], sA[1]), fmaxf(sA[2], sA[3]));
    float xa1 = fmaxf(fmaxf(sA[4], sA[5]), fmaxf(sA[6], sA[7]));
    float xa2 = fmaxf(fmaxf(sA[8], sA[9]), fmaxf(sA[10], sA[11]));
    float xa3 = fmaxf(fmaxf(sA[12], sA[13]), fmaxf(sA[14], sA[15]));
    float mxA = fmaxf(fmaxf(xa0, xa1), fmaxf(xa2, xa3));
    float xb0 = fmaxf(fmaxf(sB[0], sB[1]), fmaxf(sB[2], sB[3]));
    float xb1 = fmaxf(fmaxf(sB[4], sB[5]), fmaxf(sB[6], sB[7]));
    float xb2 = fmaxf(fmaxf(sB[8], sB[9]), fmaxf(sB[10], sB[11]));
    float xb3 = fmaxf(fmaxf(sB[12], sB[13]), fmaxf(sB[14], sB[15]));
    float mxB = fmaxf(fmaxf(xb0, xb1), fmaxf(xb2, xb3));
    {
      union { float f; u32 u; } ca, cb;
      ca.f = mxA; cb.f = mxB;
      u32x2 swa = __builtin_amdgcn_permlane32_swap(ca.u, ca.u, false, false);
      u32x2 swb = __builtin_amdgcn_permlane32_swap(cb.u, cb.u, false, false);
      union { u32 u; float f; } r0, r1;
      r0.u = swa[0]; r1.u = swa[1]; mxA = fmaxf(r0.f, r1.f);
      r0.u = swb[0]; r1.u = swb[1]; mxB = fmaxf(r0.f, r1.f);
    }
    bool ok = (mxA <= mA + 8.f) && (mxB <= mB + 8.f);
    if (!__all(ok)) {
      float mnA = fmaxf(mA, mxA), mnB = fmaxf(mB, mxB);
      float aA = fexp2(mA - mnA), aB = fexp2(mB - mnB);
      lA *= aA; lB *= aB;
#pragma unroll
      for (int ct = 0; ct < 4; ++ct)
#pragma unroll
        for (int r = 0; r < 16; ++r) {
          accA[ct][r] *= aA;
          accB[ct][r] *= aB;
        }
      mA = mnA; mB = mnB;
    }
    // ---- subtile A: P, pack, PV ----
    {
      float p[16];
#pragma unroll
      for (int r = 0; r < 16; ++r) p[r] = fexp2(sA[r] - mA);
      float s0 = (p[0] + p[1]) + (p[2] + p[3]);
      float s1 = (p[4] + p[5]) + (p[6] + p[7]);
      float s2 = (p[8] + p[9]) + (p[10] + p[11]);
      float s3 = (p[12] + p[13]) + (p[14] + p[15]);
      float sum = (s0 + s1) + (s2 + s3);
      union { float f; u32 u; } cv; cv.f = sum;
      u32x2 sw = __builtin_amdgcn_permlane32_swap(cv.u, cv.u, false, false);
      union { u32 u; float f; } r0, r1; r0.u = sw[0]; r1.u = sw[1];
      lA += r0.f + r1.f;
      u32 dw0 = (u32)__builtin_amdgcn_cvt_pk_fp8_f32(p[0], p[1], 0, false);
      dw0 = (u32)__builtin_amdgcn_cvt_pk_fp8_f32(p[2], p[3], (int)dw0, true);
      u32 dw1 = (u32)__builtin_amdgcn_cvt_pk_fp8_f32(p[4], p[5], 0, false);
      dw1 = (u32)__builtin_amdgcn_cvt_pk_fp8_f32(p[6], p[7], (int)dw1, true);
      u32 dw2 = (u32)__builtin_amdgcn_cvt_pk_fp8_f32(p[8], p[9], 0, false);
      dw2 = (u32)__builtin_amdgcn_cvt_pk_fp8_f32(p[10], p[11], (int)dw2, true);
      u32 dw3 = (u32)__builtin_amdgcn_cvt_pk_fp8_f32(p[12], p[13], 0, false);
      dw3 = (u32)__builtin_amdgcn_cvt_pk_fp8_f32(p[14], p[15], (int)dw3, true);
      u32x2 sw0 = __builtin_amdgcn_permlane32_swap(dw0, dw1, false, false);
      u32x2 sw1 = __builtin_amdgcn_permlane32_swap(dw2, dw3, false, false);
      union { uint2 u; long long l_; } pf0, pf1;
      pf0.u.x = sw0[0]; pf0.u.y = sw0[1];
      pf1.u.x = sw1[0]; pf1.u.y = sw1[1];
#pragma unroll
      for (int ct = 0; ct < 4; ++ct) {
        union { uint2 u; long long l_; } v0u, v1u;
        v0u.u = vr[2 * ct]; v1u.u = vr[2 * ct + 1];
        accA[ct] = __builtin_amdgcn_mfma_f32_32x32x16_fp8_fp8(v0u.l_, pf0.l_, accA[ct], 0, 0, 0);
        accA[ct] = __builtin_amdgcn_mfma_f32_32x32x16_fp8_fp8(v1u.l_, pf1.l_, accA[ct], 0, 0, 0);
      }
    }
    // ---- subtile B: P, pack, PV ----
    {
      float p[16];
#pragma unroll
      for (int r = 0; r < 16; ++r) p[r] = fexp2(sB[r] - mB);
      float s0 = (p[0] + p[1]) + (p[2] + p[3]);
      float s1 = (p[4] + p[5]) + (p[6] + p[7]);
      float s2 = (p[8] + p[9]) + (p[10] + p[11]);
      float s3 = (p[12] + p[13]) + (p[14] + p[15]);
      float sum = (s0 + s1) + (s2 + s3);
      union { float f; u32 u; } cv; cv.f = sum;
      u32x2 sw = __builtin_amdgcn_permlane32_swap(cv.u, cv.u, false, false);
      union { u32 u; float f; } r0, r1; r0.u = sw[0]; r1.u = sw[1];
      lB += r0.f + r1.f;
      u32 dw0 = (u32)__builtin_amdgcn_cvt_pk_fp8_f32(p[0], p[1], 0, false);
      dw0 = (u32)__builtin_amdgcn_cvt_pk_fp8_f32(p[2], p[3], (int)dw0, true);
      u32 dw1 = (u32)__builtin_amdgcn_cvt_pk_fp8_f32(p[4], p[5], 0, false);
      dw1 = (u32)__builtin_amdgcn_cvt_pk_fp8_f32(p[6], p[7], (int)dw1, true);
      u32 dw2 = (u32)__builtin_amdgcn_cvt_pk_fp8_f32(p[8], p[9], 0, false);
      dw2 = (u32)__builtin_amdgcn_cvt_pk_fp8_f32(p[10], p[11], (int)dw2, true);
      u32 dw3 = (u32)__builtin_amdgcn_cvt_pk_fp8_f32(p[12], p[13], 0, false);
      dw3 = (u32)__builtin_amdgcn_cvt_pk_fp8_f32(p[14], p[15], (int)dw3, true);
      u32x2 sw0 = __builtin_amdgcn_permlane32_swap(dw0, dw1, false, false);
      u32x2 sw1 = __builtin_amdgcn_permlane32_swap(dw2, dw3, false, false);
      union { uint2 u; long long l_; } pf0, pf1;
      pf0.u.x = sw0[0]; pf0.u.y = sw0[1];
      pf1.u.x = sw1[0]; pf1.u.y = sw1[1];
#pragma unroll
      for (int ct = 0; ct < 4; ++ct) {
        union { uint2 u; long long l_; } v0u, v1u;
        v0u.u = vr[2 * ct]; v1u.u = vr[2 * ct + 1];
        accB[ct] = __builtin_amdgcn_mfma_f32_32x32x16_fp8_fp8(v0u.l_, pf0.l_, accB[ct], 0, 0, 0);
        accB[ct] = __builtin_amdgcn_mfma_f32_32x32x16_fp8_fp8(v1u.l_, pf1.l_, accB[ct], 0, 0, 0);
      }
    }
  }

  float g0 = gamma[0];
  // ---- combine pass macro: 8 -> 4 -> 1 waves, then epilogue ----
#define COMBINE_PASS(ACC, MV, LV, QOFF)                                       \
  __syncthreads();                                                            \
  if (lane < 32) { lm[wv][q] = MV; ll[wv][q] = LV; }                          \
  if (wv >= 4) {                                                              \
    int w = wv - 4;                                                           \
    _Pragma("unroll")                                                         \
    for (int ct = 0; ct < 4; ++ct)                                            \
      _Pragma("unroll")                                                       \
      for (int q4 = 0; q4 < 4; ++q4) {                                        \
        uint2 pkd;                                                            \
        pkd.x = pk2(ACC[ct][q4 * 4 + 0], ACC[ct][q4 * 4 + 1]);                \
        pkd.y = pk2(ACC[ct][q4 * 4 + 2], ACC[ct][q4 * 4 + 3]);                \
        *(uint2*)&buf[w][q][16 * ct + 4 * q4 + 2 * hi] = pkd;                 \
      }                                                                       \
  }                                                                           \
  __syncthreads();                                                            \
  if (wv < 4) {                                                               \
    float m2 = lm[wv + 4][q], l2 = ll[wv + 4][q];                             \
    float mm = fmaxf(MV, m2);                                                 \
    float fa = fexp2(MV - mm), fb = fexp2(m2 - mm);                           \
    _Pragma("unroll")                                                         \
    for (int ct = 0; ct < 4; ++ct)                                            \
      _Pragma("unroll")                                                       \
      for (int q4 = 0; q4 < 4; ++q4) {                                        \
        uint2 pr = *(const uint2*)&buf[wv][q][16 * ct + 4 * q4 + 2 * hi];     \
        ACC[ct][q4 * 4 + 0] = ACC[ct][q4 * 4 + 0] * fa + bflo(pr.x) * fb;     \
        ACC[ct][q4 * 4 + 1] = ACC[ct][q4 * 4 + 1] * fa + bfhi(pr.x) * fb;     \
        ACC[ct][q4 * 4 + 2] = ACC[ct][q4 * 4 + 2] * fa + bflo(pr.y) * fb;     \
        ACC[ct][q4 * 4 + 3] = ACC[ct][q4 * 4 + 3] * fa + bfhi(pr.y) * fb;     \
      }                                                                       \
    LV = LV * fa + l2 * fb;                                                   \
    MV = mm;                                                                  \
  }                                                                           \
  __syncthreads();                                                            \
  if (wv < 4 && lane < 32) { lm[wv][q] = MV; ll[wv][q] = LV; }                \
  __syncthreads();                                                            \
  if (wv < 4) {                                                               \
    float ms = fmaxf(fmaxf(lm[0][q], lm[1][q]), fmaxf(lm[2][q], lm[3][q]));   \
    float f = fexp2(MV - ms);                                                 \
    _Pragma("unroll")                                                         \
    for (int ct = 0; ct < 4; ++ct)                                            \
      _Pragma("unroll")                                                       \
      for (int q4 = 0; q4 < 4; ++q4) {                                        \
        uint2 pkd;                                                            \
        pkd.x = pk2(ACC[ct][q4 * 4 + 0] * f, ACC[ct][q4 * 4 + 1] * f);        \
        pkd.y = pk2(ACC[ct][q4 * 4 + 2] * f, ACC[ct][q4 * 4 + 3] * f);        \
        *(uint2*)&buf[wv][q][16 * ct + 4 * q4 + 2 * hi] = pkd;                \
      }                                                                       \
  }                                                                           \
  __syncthreads();                                                            \
  {                                                                           \
    int qe = t & 31, cg = t >> 5;                                             \
    float m0 = lm[0][qe], m1 = lm[1][qe], m2 = lm[2][qe], m3 = lm[3][qe];     \
    float ms = fmaxf(fmaxf(m0, m1), fmaxf(m2, m3));                           \
    float ls = ll[0][qe] * fexp2(m0 - ms) + ll[1][qe] * fexp2(m1 - ms)        \
             + ll[2][qe] * fexp2(m2 - ms) + ll[3][qe] * fexp2(m3 - ms);       \
    float inv = 1.f / ls;                                                     \
    float sacc[8];                                                            \
    _Pragma("unroll")                                                         \
    for (int j = 0; j < 8; ++j) sacc[j] = 0.f;                                \
    _Pragma("unroll")                                                         \
    for (int w = 0; w < 4; ++w) {                                             \
      uint4 r = *(const uint4*)&buf[w][qe][cg * 4];                           \
      sacc[0] += bflo(r.x); sacc[1] += bfhi(r.x);                             \
      sacc[2] += bflo(r.y); sacc[3] += bfhi(r.y);                             \
      sacc[4] += bflo(r.z); sacc[5] += bfhi(r.z);                             \
      sacc[6] += bflo(r.w); sacc[7] += bfhi(r.w);                             \
    }                                                                         \
    _Pragma("unroll")                                                         \
    for (int j = 0; j < 8; ++j) {                                             \
      size_t adr = (((size_t)b * 128) + cg * 8 + j) * 4096 + q0 + (QOFF) + qe;\
      out[adr] = g0 * sacc[j] * inv + xp[adr];                                \
    }                                                                         \
  }

  COMBINE_PASS(accA, mA, lA, 0)
  COMBINE_PASS(accB, mB, lB, 32)
#undef COMBINE_PASS
}

// ---------------------------------------------------------------------------
extern "C" void kernel_launch(void* const* d_in, const int* in_sizes, int n_in,
                              void* d_out, int out_size, void* d_ws, size_t ws_size,
                              hipStream_t stream) {
  const float* x     = (const float*)d_in[0];
  const float* Wq    = (const float*)d_in[1];
  const float* bq    = (const float*)d_in[2];
  const float* Wk    = (const float*)d_in[3];
  const float* bk    = (const float*)d_in[4];
  const float* Wv    = (const float*)d_in[5];
  const float* bv    = (const float*)d_in[6];
  const float* gamma = (const float*)d_in[7];
  const float* pos   = (const float*)d_in[8];
  float* out = (float*)d_out;

  char* ws = (char*)d_ws;
  float* xp  = (float*)ws;                          //  8,388,608 B  f32 [4][128][4096]
  u16* qw    = (u16*)(ws + 8388608);                //  1,048,576 B  bf16 [4][4096][32]
  u16* kw    = (u16*)(ws + 9437184);                //  1,048,576 B  bf16 [4][4096][32]
  u8*  v2    = (u8*)(ws + 10485760);                //  2,097,152 B  fp8 [4][128][128][32]

  k_pp<<<dim3(64, 4), 512, 0, stream>>>(x, pos, Wq, bq, Wk, bk, Wv, bv,
                                        xp, qw, kw, v2);
  k_attn<<<dim3(64, 4), 512, 0, stream>>>(qw, kw, v2, xp, gamma, out);
}